// Round 9
// baseline (85.812 us; speedup 1.0000x reference)
//
#include <hip/hip_runtime.h>

typedef __attribute__((ext_vector_type(8))) short short8;
typedef __attribute__((ext_vector_type(4))) short short4v;
typedef __attribute__((ext_vector_type(4))) float f32x4;

#define MFMA_B16(a, b, c) __builtin_amdgcn_mfma_f32_16x16x32_bf16((a), (b), (c), 0, 0, 0)

#define NTOK 2048
#define DM 256
#define NB4 4
#define HD 64

__device__ __forceinline__ short f2bf(float f) {
  union { float f; unsigned u; } x;
  x.f = f;
  unsigned r = x.u + 0x7fffu + ((x.u >> 16) & 1u);
  return (short)(r >> 16);
}
__device__ __forceinline__ float bf2f(short s) {
  union { unsigned u; float f; } x;
  x.u = ((unsigned)(unsigned short)s) << 16;
  return x.f;
}

// async global->LDS, 16B per lane. LDS dest = uniform base + lane*16 (HW).
__device__ __forceinline__ void gload16(const short* g, short* l) {
  __builtin_amdgcn_global_load_lds(
      (const __attribute__((address_space(1))) void*)g,
      (__attribute__((address_space(3))) void*)l, 16, 0, 0);
}

// y<12: fp32 [tau][b][c][n] -> bf16 XT [tau][b][n][c]. Full-line reads.
// y==12: weights fp32->bf16; wm column-permuted to head-major:
//   W'[c][i'] = wm[c][4*(i'&63) + (i'>>6)]  (i' = 64h + d)
__global__ __launch_bounds__(256) void k_pre(const float* __restrict__ q,
    const float* __restrict__ k, const float* __restrict__ v,
    const float* __restrict__ w0, const float* __restrict__ w1,
    const float* __restrict__ w2, const float* __restrict__ w3,
    short* __restrict__ xt, short* __restrict__ wbf) {
  int y = blockIdx.y;
  int t = blockIdx.x * 256 + threadIdx.x;   // 0..16383 (grid.x = 64)
  if (y < 12) {
    int tau = y >> 2, b = y & 3;
    const float* src = (tau == 0) ? q : (tau == 1) ? k : v;
    short* dst = xt + ((size_t)tau * NB4 + b) * ((size_t)NTOK * DM);
    int n4 = (t & 15) | ((t >> 9) << 4);    // 0..511
    int c8 = (t >> 4) & 31;
    const float* s = src + ((size_t)b * DM + c8 * 8) * NTOK + n4 * 4;
    float4 rows[8];
#pragma unroll
    for (int j = 0; j < 8; j++) rows[j] = *(const float4*)(s + (size_t)j * NTOK);
#pragma unroll
    for (int e = 0; e < 4; e++) {
      short8 r;
#pragma unroll
      for (int j = 0; j < 8; j++)
        r[j] = f2bf(e == 0 ? rows[j].x : e == 1 ? rows[j].y : e == 2 ? rows[j].z : rows[j].w);
      *(short8*)(dst + (size_t)(n4 * 4 + e) * DM + c8 * 8) = r;
    }
  } else {
    int tau = t >> 12;
    int off = (t << 4) & 65535;
    int c = off >> 8, ip = off & 255;
    const float* ws4[4] = {w0, w1, w2, w3};
    const float* srow = ws4[tau] + (size_t)c * 256;
#pragma unroll
    for (int half = 0; half < 2; half++) {
      short8 r;
#pragma unroll
      for (int j = 0; j < 8; j++) {
        int i2 = ip + half * 8 + j;
        r[j] = (tau == 3) ? f2bf(srow[4 * (i2 & 63) + (i2 >> 6)]) : f2bf(srow[i2]);
      }
      *(short8*)(wbf + (size_t)tau * 65536 + off + half * 8) = r;
    }
  }
}

// Fragment-linear layouts (lane = hi*16+lo):
//  Q/K frag: [bh][n16(128)][f(2)][lane(64)][j(8)]  elem = X[n=n16*16+lo][d=f*32+hi*8+j]
//  V  frag:  [bh][m32(64)][db(4)][lane(64)][j(8)]  elem = V[d=db*16+lo][m=m32*32+hi*8+j]
// One block = 64 n-rows x ALL 256 c (c0-merge: XT read exactly once).
// tau 0/1 (Q/K): C^T GEMM, wave=16n x 256c, acc[16]. Q pre-scaled log2e/8.
// tau 2   (V)  : C GEMM, wave=64c x 64n, acc[4][4].
__global__ __launch_bounds__(256, 4) void k_proj(const short* __restrict__ xt3,
    const short* __restrict__ wbf, const float* __restrict__ bq,
    const float* __restrict__ bk, const float* __restrict__ bv,
    short* __restrict__ qt, short* __restrict__ kt, short* __restrict__ vt) {
  int z = blockIdx.y, b = z & 3, tau = z >> 2;
  const short* x = xt3 + ((size_t)tau * NB4 + b) * ((size_t)NTOK * DM);
  const short* W = wbf + (size_t)tau * 65536;
  const float* bias = (tau == 0) ? bq : (tau == 1) ? bk : bv;
  int n0 = blockIdx.x * 64;
  int lane = threadIdx.x & 63, w = threadIdx.x >> 6;
  int lo = lane & 15, hi = lane >> 4;
  if (tau < 2) {
    short* out = tau ? kt : qt;
    float scale = tau ? 1.0f : (0.125f * 1.44269504f);  // fold 1/sqrt(64), log2e into Q
    f32x4 acc[16] = {};
    const short* arow = x + (size_t)(n0 + 16 * w + lo) * DM + hi * 8;
    const short* b0 = W + (size_t)lo * DM + hi * 8;
#pragma unroll
    for (int i0 = 0; i0 < DM; i0 += 32) {
      short8 a = *(const short8*)(arow + i0);
#pragma unroll
      for (int cb = 0; cb < 16; cb++) {
        short8 bb = *(const short8*)(b0 + (size_t)cb * 16 * DM + i0);
        acc[cb] = MFMA_B16(a, bb, acc[cb]);
      }
    }
#pragma unroll
    for (int cb = 0; cb < 16; cb++) {
      int c = 16 * cb + lo;
      float bvv = bias[c];
      int h = c & 3, d = c >> 2;
      int f = d >> 5, hif = (d >> 3) & 3, j = d & 7;
      size_t n16 = (size_t)(b * 4 + h) * 128 + (n0 >> 4) + w;
      short* ob = out + ((n16 * 2 + f) * 64 + hif * 16 + 4 * hi) * 8 + j;
#pragma unroll
      for (int r = 0; r < 4; r++)
        ob[r * 8] = f2bf((acc[cb][r] + bvv) * scale);
    }
  } else {
    f32x4 acc[4][4] = {};   // [cb][nb]
    const short* arow = W + (size_t)(64 * w + lo) * DM + hi * 8;
    const short* brow = x + (size_t)(n0 + lo) * DM + hi * 8;
#pragma unroll
    for (int i0 = 0; i0 < DM; i0 += 32) {
      short8 bbr[4];
#pragma unroll
      for (int nb = 0; nb < 4; nb++)
        bbr[nb] = *(const short8*)(brow + (size_t)nb * 16 * DM + i0);
#pragma unroll
      for (int cb = 0; cb < 4; cb++) {
        short8 a = *(const short8*)(arow + (size_t)cb * 16 * DM + i0);
#pragma unroll
        for (int nb = 0; nb < 4; nb++)
          acc[cb][nb] = MFMA_B16(a, bbr[nb], acc[cb][nb]);
      }
    }
#pragma unroll
    for (int cb = 0; cb < 4; cb++) {
#pragma unroll
      for (int r = 0; r < 4; r++) {
        int c = 64 * w + 16 * cb + 4 * hi + r;
        float bvv = bias[c];
        int h = c & 3, d = c >> 2;
        int db = d >> 4, rowd = d & 15;
        size_t bb64 = (size_t)(b * 4 + h) * 64;
#pragma unroll
        for (int nb = 0; nb < 4; nb++) {
          int n = n0 + 16 * nb + lo;
          int m32 = n >> 5, him = (n >> 3) & 3, jm = n & 7;
          vt[(((bb64 + m32) * 4 + db) * 64 + him * 16 + rowd) * 8 + jm] =
              f2bf(acc[cb][nb][r] + bvv);
        }
      }
    }
  }
}

// Flash attention, 256-row Q tiles (2 qs-subtiles/wave), 8 waves.
// Swapped QK^T (A=K, B=Q). No-max softmax. K/V frags read once per tile,
// reused across qs. Row-sum via ones-MFMA. P packed with v_cvt_pk_bf16_f32.
template <int SPLIT>
__global__ __launch_bounds__(512, 4) void k_attn(const short* __restrict__ qt,
    const short* __restrict__ kt, const short* __restrict__ vt,
    short* __restrict__ opart, float* __restrict__ ml) {
  __shared__ __align__(16) short Ks[2][4096];      // [mb(4)][f(2)][lane][8]
  __shared__ __align__(16) short Vs[2][4096];      // [ks(2)][db(4)][lane][8]
  __shared__ __align__(16) short Ps[8][2][16][72]; // per-wave,per-qs [n][m+pad]
  int z = blockIdx.z, b = z & 3, chunk = z >> 2;
  int h = blockIdx.y, n0 = blockIdx.x * 256;
  int lane = threadIdx.x & 63, w = threadIdx.x >> 6;
  int lo = lane & 15, hi = lane >> 4;
  const int CH = NTOK / SPLIT;
  const int kv0 = chunk * CH;
  int bh = b * 4 + h;
  const short* Qf = qt + (size_t)bh * 131072;
  const short* Kf = kt + (size_t)bh * 131072;
  const short* Vf = vt + (size_t)bh * 131072;
  short8 qf0[2], qf1[2];
#pragma unroll
  for (int qs = 0; qs < 2; qs++) {
    size_t n16 = (size_t)(n0 >> 4) + 8 * qs + w;
    qf0[qs] = *(const short8*)(Qf + ((n16 * 2 + 0) * 64 + lane) * 8);
    qf1[qs] = *(const short8*)(Qf + ((n16 * 2 + 1) * 64 + lane) * 8);
  }
  short8 ones;
#pragma unroll
  for (int j = 0; j < 8; j++) ones[j] = (short)0x3F80;   // bf16 1.0
  f32x4 acc[2][4] = {};
  f32x4 accl[2] = {};

  int nt = CH >> 6, buf = 0;
  {
    const short* ksrc = Kf + (size_t)(kv0 >> 4) * 1024;
    const short* vsrc = Vf + (size_t)(kv0 >> 5) * 2048;
    gload16(ksrc + w * 512 + lane * 8, &Ks[0][w * 512]);
    gload16(vsrc + w * 512 + lane * 8, &Vs[0][w * 512]);
  }
  __syncthreads();   // vmcnt drain -> staged data visible

  for (int t = 0; t < nt; t++) {
    int m0 = kv0 + (t << 6);
    if (t + 1 < nt) {
      const short* ksrc = Kf + (size_t)((m0 + 64) >> 4) * 1024;
      const short* vsrc = Vf + (size_t)((m0 + 64) >> 5) * 2048;
      gload16(ksrc + w * 512 + lane * 8, &Ks[buf ^ 1][w * 512]);
      gload16(vsrc + w * 512 + lane * 8, &Vs[buf ^ 1][w * 512]);
    }
    // ---- phase 1: S = K^T Q for both qs, K-frags read once ----
    f32x4 s[2][4];
    __builtin_amdgcn_s_setprio(1);
#pragma unroll
    for (int mb = 0; mb < 4; mb++) {
      short8 kf0 = *(const short8*)&Ks[buf][(mb * 2 + 0) * 512 + lane * 8];
      short8 kf1 = *(const short8*)&Ks[buf][(mb * 2 + 1) * 512 + lane * 8];
#pragma unroll
      for (int qs = 0; qs < 2; qs++) {
        f32x4 zz = {};
        zz = MFMA_B16(kf0, qf0[qs], zz);          // swapped: rows=m, cols=n
        s[qs][mb] = MFMA_B16(kf1, qf1[qs], zz);
      }
    }
    __builtin_amdgcn_s_setprio(0);
    // ---- phase 2: P = exp2(S) -> bf16, packed pair-store to LDS ----
#pragma unroll
    for (int qs = 0; qs < 2; qs++) {
#pragma unroll
      for (int mb = 0; mb < 4; mb++) {
        float e0 = exp2f(s[qs][mb][0]);
        float e1 = exp2f(s[qs][mb][1]);
        float e2 = exp2f(s[qs][mb][2]);
        float e3 = exp2f(s[qs][mb][3]);
        unsigned p01, p23;
        asm("v_cvt_pk_bf16_f32 %0, %1, %2" : "=v"(p01) : "v"(e0), "v"(e1));
        asm("v_cvt_pk_bf16_f32 %0, %1, %2" : "=v"(p23) : "v"(e2), "v"(e3));
        uint2 pk;
        pk.x = p01;
        pk.y = p23;
        *(uint2*)&Ps[w][qs][lo][16 * mb + 4 * hi] = pk;  // m = 16mb+4hi+r, n = lo
      }
    }
    // ---- phase 3: PV + ones-MFMA row-sum; V-frags read once ----
    __builtin_amdgcn_s_setprio(1);
#pragma unroll
    for (int ks_i = 0; ks_i < 2; ks_i++) {
      short8 pa0 = *(const short8*)(&Ps[w][0][lo][32 * ks_i + 8 * hi]);
      short8 pa1 = *(const short8*)(&Ps[w][1][lo][32 * ks_i + 8 * hi]);
      accl[0] = MFMA_B16(pa0, ones, accl[0]);
      accl[1] = MFMA_B16(pa1, ones, accl[1]);
#pragma unroll
      for (int db = 0; db < 4; db++) {
        short8 vf = *(const short8*)&Vs[buf][(ks_i * 4 + db) * 512 + lane * 8];
        acc[0][db] = MFMA_B16(pa0, vf, acc[0][db]);
        acc[1][db] = MFMA_B16(pa1, vf, acc[1][db]);
      }
    }
    __builtin_amdgcn_s_setprio(0);
    __syncthreads();   // staging of buf^1 complete + all reads of buf done
    buf ^= 1;
  }

  size_t rbase = (((size_t)chunk * NB4 + b) * 4 + h) * NTOK;
#pragma unroll
  for (int qs = 0; qs < 2; qs++) {
    int nq = n0 + 128 * qs + 16 * w;
    if (lo == 0) {
#pragma unroll
      for (int r = 0; r < 4; r++)
        ml[rbase + nq + 4 * hi + r] = accl[qs][r];   // cols identical; any lo
    }
#pragma unroll
    for (int r = 0; r < 4; r++) {
      size_t row = rbase + nq + 4 * hi + r;
#pragma unroll
      for (int db = 0; db < 4; db++)
        opart[row * HD + 16 * db + lo] = f2bf(acc[qs][db][r]);
    }
  }
}

// Fused combine + output GEMM, c0-merged: block = 32 n-rows x ALL 256 c
// (Opart read exactly once). Additive combine -> As (fragment-linear,
// XOR-swizzled); wave = 64c x 32n, acc[4][2]. fp32 out.
template <int NCH>
__global__ __launch_bounds__(256, 4) void k_out(const short* __restrict__ W,
    const short* __restrict__ opart, const float* __restrict__ ml,
    const float* __restrict__ bias, float* __restrict__ outp) {
  __shared__ __align__(16) short As[8192];  // [nb(2)][i32(8)][64][8], swizzled
  int b = blockIdx.y;
  int n0 = blockIdx.x * 32;
  int t = threadIdx.x;
  int lane = t & 63, w = t >> 6;
  int lo16 = lane & 15, hi = lane >> 4;
  {
    int d8 = t & 7, h = (t >> 3) & 3, nb8 = t >> 5;   // nb8 0..7
    int i32 = 2 * h + (d8 >> 2), fhi = d8 & 3;        // fragment coords of i'
#pragma unroll
    for (int it = 0; it < 4; it++) {
      int noff = nb8 * 4 + it;                        // 0..31
      int n = n0 + noff;
      int nb = noff >> 4, flo = noff & 15;
      size_t row0 = ((size_t)b * 4 + h) * NTOK + n;   // chunk 0
      float l = ml[row0];
      float o[8];
      short8 o0 = *(const short8*)(opart + row0 * HD + d8 * 8);
#pragma unroll
      for (int j = 0; j < 8; j++) o[j] = bf2f(o0[j]);
#pragma unroll
      for (int ch = 1; ch < NCH; ch++) {
        size_t rowc = row0 + (size_t)ch * 16 * NTOK;
        l += ml[rowc];
        short8 oc = *(const short8*)(opart + rowc * HD + d8 * 8);
#pragma unroll
        for (int j = 0; j < 8; j++) o[j] += bf2f(oc[j]);
      }
      float inv = 1.0f / l;
      short8 res;
#pragma unroll
      for (int j = 0; j < 8; j++) res[j] = f2bf(o[j] * inv);
      int frag = ((nb * 8 + i32) * 64 + fhi * 16 + flo) ^ d8;  // d8==fhi|((i32&1)<<2)
      *(short8*)(As + frag * 8) = res;
    }
  }
  __syncthreads();
  f32x4 acc[4][2] = {};   // [cb][nb]
  const short* arow = W + (size_t)(64 * w + lo16) * DM + hi * 8;
#pragma unroll
  for (int ks = 0; ks < 8; ks++) {
    int sr = hi | ((ks & 1) << 2);
    short8 bbr[2];
#pragma unroll
    for (int nb = 0; nb < 2; nb++) {
      int frag = ((nb * 8 + ks) * 64 + lane) ^ sr;
      bbr[nb] = *(const short8*)(As + frag * 8);
    }
#pragma unroll
    for (int cb = 0; cb < 4; cb++) {
      short8 a = *(const short8*)(arow + (size_t)cb * 16 * DM + ks * 32);
#pragma unroll
      for (int nb = 0; nb < 2; nb++)
        acc[cb][nb] = MFMA_B16(a, bbr[nb], acc[cb][nb]);
    }
  }
#pragma unroll
  for (int cb = 0; cb < 4; cb++) {
#pragma unroll
    for (int r = 0; r < 4; r++) {
      int c = 64 * w + 16 * cb + 4 * hi + r;
      float bvv = bias[c];
#pragma unroll
      for (int nb = 0; nb < 2; nb++) {
        int n = n0 + 16 * nb + lo16;
        outp[((size_t)b * DM + c) * NTOK + n] = acc[cb][nb][r] + bvv;
      }
    }
  }
}

extern "C" void kernel_launch(void* const* d_in, const int* in_sizes, int n_in,
                              void* d_out, int out_size, void* d_ws, size_t ws_size,
                              hipStream_t stream) {
  const float* q  = (const float*)d_in[0];
  const float* k  = (const float*)d_in[1];
  const float* v  = (const float*)d_in[2];
  const float* wq = (const float*)d_in[3];
  const float* bq = (const float*)d_in[4];
  const float* wk = (const float*)d_in[5];
  const float* bk = (const float*)d_in[6];
  const float* wv = (const float*)d_in[7];
  const float* bv = (const float*)d_in[8];
  const float* wm = (const float*)d_in[9];
  const float* bm = (const float*)d_in[10];

  char* ws = (char*)d_ws;
  const size_t MB = 1024 * 1024;
  short* XT  = (short*)(ws);              // 3 x 4MB   [tau][b][n][i]
  short* Qt  = (short*)(ws + 12 * MB);    // 4MB  Q fragments
  short* Kt  = (short*)(ws + 16 * MB);    // 4MB  K fragments
  short* Vt  = (short*)(ws + 20 * MB);    // 4MB  V fragments
  short* Wbf = (short*)(ws + 24 * MB);    // 4 x 128KB
  float* ML    = (float*)(ws + 25 * MB);  // 4 chunks x 128KB row sums l
  short* Opart = (short*)(ws + 26 * MB);  // 4 chunks x 4MB bf16 partial O

  k_pre<<<dim3(64, 13), 256, 0, stream>>>(q, k, v, wq, wk, wv, wm, XT, Wbf);
  k_proj<<<dim3(32, 12), 256, 0, stream>>>(XT, Wbf, bq, bk, bv, Qt, Kt, Vt);

  if (ws_size >= 42 * MB) {
    k_attn<4><<<dim3(8, 4, 16), 512, 0, stream>>>(Qt, Kt, Vt, Opart, ML);
    k_out<4><<<dim3(64, 4), 256, 0, stream>>>(Wbf + 3 * 65536, Opart, ML, bm, (float*)d_out);
  } else {
    k_attn<1><<<dim3(8, 4, 4), 512, 0, stream>>>(Qt, Kt, Vt, Opart, ML);
    k_out<1><<<dim3(64, 4), 256, 0, stream>>>(Wbf + 3 * 65536, Opart, ML, bm, (float*)d_out);
  }

  (void)in_sizes; (void)n_in; (void)out_size; (void)ws_size;
}

// Round 10
// 69.815 us; speedup vs baseline: 1.2291x; 1.2291x over previous
//
#include <hip/hip_runtime.h>

typedef __attribute__((ext_vector_type(8))) short short8;
typedef __attribute__((ext_vector_type(4))) short short4v;
typedef __attribute__((ext_vector_type(4))) float f32x4;

#define MFMA_B16(a, b, c) __builtin_amdgcn_mfma_f32_16x16x32_bf16((a), (b), (c), 0, 0, 0)

#define NTOK 2048
#define DM 256
#define NB4 4
#define HD 64

__device__ __forceinline__ short f2bf(float f) {
  union { float f; unsigned u; } x;
  x.f = f;
  unsigned r = x.u + 0x7fffu + ((x.u >> 16) & 1u);
  return (short)(r >> 16);
}
__device__ __forceinline__ float bf2f(short s) {
  union { unsigned u; float f; } x;
  x.u = ((unsigned)(unsigned short)s) << 16;
  return x.f;
}

// async global->LDS, 16B per lane. LDS dest = uniform base + lane*16 (HW).
__device__ __forceinline__ void gload16(const short* g, short* l) {
  __builtin_amdgcn_global_load_lds(
      (const __attribute__((address_space(1))) void*)g,
      (__attribute__((address_space(3))) void*)l, 16, 0, 0);
}

// Weights fp32->bf16; wm column-permuted to head-major:
//   W'[c][i'] = wm[c][4*(i'&63) + (i'>>6)]  (i' = 64h + d)
__global__ __launch_bounds__(256) void k_wpre(const float* __restrict__ w0,
    const float* __restrict__ w1, const float* __restrict__ w2,
    const float* __restrict__ w3, short* __restrict__ wbf) {
  int t = blockIdx.x * 256 + threadIdx.x;   // grid 32 -> 8192 threads, 32 elems each
  const float* ws4[4] = {w0, w1, w2, w3};
  int base = t * 32;
#pragma unroll
  for (int blk = 0; blk < 4; blk++) {
    int off = base + blk * 8;
    int tau = off >> 16;
    int rest = off & 65535;
    int c = rest >> 8, ip = rest & 255;
    const float* srow = ws4[tau] + (size_t)c * 256;
    short8 r;
#pragma unroll
    for (int j = 0; j < 8; j++) {
      int i2 = ip + j;
      r[j] = (tau == 3) ? f2bf(srow[4 * (i2 & 63) + (i2 >> 6)]) : f2bf(srow[i2]);
    }
    *(short8*)(wbf + off) = r;
  }
}

// Fused transpose + projection. Block = 64 n-rows x all 256 c, one (tau,b).
// Stage: fp32 X[b][c][n0..n0+63] -> bf16 -> LDS As in MFMA fragment-linear
// order with XOR swizzle s = iG&7 (same verified algebra as k_out's As).
// Then: tau 0/1 (Q/K): D[n][c] = mfma(X,W), frag-layout out, Q scaled log2e/8.
//       tau 2   (V)  : D[c][n] = mfma(W,X), V-frag-layout out.
// Fragment-linear outputs (lane = hi*16+lo):
//  Q/K: [bh][n16(128)][f(2)][lane(64)][j(8)]  elem = X[n=n16*16+lo][d=f*32+hi*8+j]
//  V:   [bh][m32(64)][db(4)][lane(64)][j(8)]  elem = V[d=db*16+lo][m=m32*32+hi*8+j]
__global__ __launch_bounds__(256, 4) void k_proj(const float* __restrict__ q,
    const float* __restrict__ k, const float* __restrict__ v,
    const short* __restrict__ wbf, const float* __restrict__ bq,
    const float* __restrict__ bk, const float* __restrict__ bv,
    short* __restrict__ qt, short* __restrict__ kt, short* __restrict__ vt) {
  __shared__ __align__(16) short As[16384];  // [nb(4)][i32(8)][64][8] swizzled, 32KB
  int z = blockIdx.y, b = z & 3, tau = z >> 2;
  const float* src = ((tau == 0) ? q : (tau == 1) ? k : v) + (size_t)b * DM * NTOK;
  const short* W = wbf + (size_t)tau * 65536;
  const float* bias = (tau == 0) ? bq : (tau == 1) ? bk : bv;
  int n0 = blockIdx.x * 64;
  int t = threadIdx.x;
  // ---- stage: read fp32 (full lines), convert, swizzled LDS write ----
  {
    int nseg = t & 15, rg = t >> 4;   // rg 0..15: 8 consecutive c-rows
#pragma unroll
    for (int outer = 0; outer < 2; outer++) {
      int iG = rg + 16 * outer;       // i-granule 0..31
      const float* s0 = src + (size_t)(iG * 8) * NTOK + n0 + nseg * 4;
      float4 rows[8];
#pragma unroll
      for (int j = 0; j < 8; j++) rows[j] = *(const float4*)(s0 + (size_t)j * NTOK);
      int i32 = iG >> 2, fhi = iG & 3, s = iG & 7;
#pragma unroll
      for (int e = 0; e < 4; e++) {
        int n = nseg * 4 + e;
        int nb = n >> 4, flo = n & 15;
        short8 r;
#pragma unroll
        for (int j = 0; j < 8; j++)
          r[j] = f2bf(e == 0 ? rows[j].x : e == 1 ? rows[j].y
                                         : e == 2 ? rows[j].z : rows[j].w);
        int frag = ((nb * 8 + i32) * 64 + fhi * 16 + flo) ^ s;
        *(short8*)(As + frag * 8) = r;
      }
    }
  }
  __syncthreads();
  // ---- GEMM: wave = 64 c x 64 n, acc[cb][nb] ----
  int lane = t & 63, w = t >> 6;
  int lo = lane & 15, hi = lane >> 4;
  f32x4 acc[4][4] = {};
  const short* wrow = W + (size_t)(64 * w + lo) * DM + hi * 8;
#pragma unroll
  for (int ks = 0; ks < 8; ks++) {
    int sr = hi | ((ks & 1) << 2);
    short8 xf[4];
#pragma unroll
    for (int nb = 0; nb < 4; nb++) {
      int frag = ((nb * 8 + ks) * 64 + lane) ^ sr;
      xf[nb] = *(const short8*)(As + frag * 8);
    }
#pragma unroll
    for (int cb = 0; cb < 4; cb++) {
      short8 wf = *(const short8*)(wrow + (size_t)cb * 16 * DM + ks * 32);
      if (tau < 2) {
#pragma unroll
        for (int nb = 0; nb < 4; nb++)
          acc[cb][nb] = MFMA_B16(xf[nb], wf, acc[cb][nb]);   // col=c, row=n
      } else {
#pragma unroll
        for (int nb = 0; nb < 4; nb++)
          acc[cb][nb] = MFMA_B16(wf, xf[nb], acc[cb][nb]);   // col=n, row=c
      }
    }
  }
  if (tau < 2) {
    short* out = tau ? kt : qt;
    float scale = tau ? 1.0f : (0.125f * 1.44269504f);  // fold 1/sqrt(64), log2e into Q
#pragma unroll
    for (int cb = 0; cb < 4; cb++) {
      int c = 64 * w + 16 * cb + lo;
      float bvv = bias[c];
      int h = c & 3, d = c >> 2;
      int f = d >> 5, hif = (d >> 3) & 3, jj = d & 7;
#pragma unroll
      for (int nb = 0; nb < 4; nb++) {
        size_t n16 = (size_t)(b * 4 + h) * 128 + (n0 >> 4) + nb;
        short* ob = out + ((n16 * 2 + f) * 64 + hif * 16 + 4 * hi) * 8 + jj;
#pragma unroll
        for (int r = 0; r < 4; r++)
          ob[r * 8] = f2bf((acc[cb][nb][r] + bvv) * scale);
      }
    }
  } else {
#pragma unroll
    for (int cb = 0; cb < 4; cb++) {
#pragma unroll
      for (int r = 0; r < 4; r++) {
        int c = 64 * w + 16 * cb + 4 * hi + r;
        float bvv = bias[c];
        int h = c & 3, d = c >> 2;
        int db = d >> 4, rowd = d & 15;
        size_t bb64 = (size_t)(b * 4 + h) * 64;
#pragma unroll
        for (int nb = 0; nb < 4; nb++) {
          int n = n0 + 16 * nb + lo;
          int m32 = n >> 5, him = (n >> 3) & 3, jm = n & 7;
          vt[(((bb64 + m32) * 4 + db) * 64 + him * 16 + rowd) * 8 + jm] =
              f2bf(acc[cb][nb][r] + bvv);
        }
      }
    }
  }
}

// Flash attention, 256-row Q tiles (2 qs-subtiles/wave), 8 waves.
// Swapped QK^T (A=K, B=Q). No-max softmax. K/V frags read once per tile,
// reused across qs. Row-sum via ones-MFMA. P packed with v_cvt_pk_bf16_f32.
template <int SPLIT>
__global__ __launch_bounds__(512, 4) void k_attn(const short* __restrict__ qt,
    const short* __restrict__ kt, const short* __restrict__ vt,
    short* __restrict__ opart, float* __restrict__ ml) {
  __shared__ __align__(16) short Ks[2][4096];      // [mb(4)][f(2)][lane][8]
  __shared__ __align__(16) short Vs[2][4096];      // [ks(2)][db(4)][lane][8]
  __shared__ __align__(16) short Ps[8][2][16][72]; // per-wave,per-qs [n][m+pad]
  int z = blockIdx.z, b = z & 3, chunk = z >> 2;
  int h = blockIdx.y, n0 = blockIdx.x * 256;
  int lane = threadIdx.x & 63, w = threadIdx.x >> 6;
  int lo = lane & 15, hi = lane >> 4;
  const int CH = NTOK / SPLIT;
  const int kv0 = chunk * CH;
  int bh = b * 4 + h;
  const short* Qf = qt + (size_t)bh * 131072;
  const short* Kf = kt + (size_t)bh * 131072;
  const short* Vf = vt + (size_t)bh * 131072;
  short8 qf0[2], qf1[2];
#pragma unroll
  for (int qs = 0; qs < 2; qs++) {
    size_t n16 = (size_t)(n0 >> 4) + 8 * qs + w;
    qf0[qs] = *(const short8*)(Qf + ((n16 * 2 + 0) * 64 + lane) * 8);
    qf1[qs] = *(const short8*)(Qf + ((n16 * 2 + 1) * 64 + lane) * 8);
  }
  short8 ones;
#pragma unroll
  for (int j = 0; j < 8; j++) ones[j] = (short)0x3F80;   // bf16 1.0
  f32x4 acc[2][4] = {};
  f32x4 accl[2] = {};

  int nt = CH >> 6, buf = 0;
  {
    const short* ksrc = Kf + (size_t)(kv0 >> 4) * 1024;
    const short* vsrc = Vf + (size_t)(kv0 >> 5) * 2048;
    gload16(ksrc + w * 512 + lane * 8, &Ks[0][w * 512]);
    gload16(vsrc + w * 512 + lane * 8, &Vs[0][w * 512]);
  }
  __syncthreads();   // vmcnt drain -> staged data visible

  for (int t = 0; t < nt; t++) {
    int m0 = kv0 + (t << 6);
    if (t + 1 < nt) {
      const short* ksrc = Kf + (size_t)((m0 + 64) >> 4) * 1024;
      const short* vsrc = Vf + (size_t)((m0 + 64) >> 5) * 2048;
      gload16(ksrc + w * 512 + lane * 8, &Ks[buf ^ 1][w * 512]);
      gload16(vsrc + w * 512 + lane * 8, &Vs[buf ^ 1][w * 512]);
    }
    // ---- phase 1: S = K^T Q for both qs, K-frags read once ----
    f32x4 s[2][4];
    __builtin_amdgcn_s_setprio(1);
#pragma unroll
    for (int mb = 0; mb < 4; mb++) {
      short8 kf0 = *(const short8*)&Ks[buf][(mb * 2 + 0) * 512 + lane * 8];
      short8 kf1 = *(const short8*)&Ks[buf][(mb * 2 + 1) * 512 + lane * 8];
#pragma unroll
      for (int qs = 0; qs < 2; qs++) {
        f32x4 zz = {};
        zz = MFMA_B16(kf0, qf0[qs], zz);          // swapped: rows=m, cols=n
        s[qs][mb] = MFMA_B16(kf1, qf1[qs], zz);
      }
    }
    __builtin_amdgcn_s_setprio(0);
    // ---- phase 2: P = exp2(S) -> bf16, packed pair-store to LDS ----
#pragma unroll
    for (int qs = 0; qs < 2; qs++) {
#pragma unroll
      for (int mb = 0; mb < 4; mb++) {
        float e0 = exp2f(s[qs][mb][0]);
        float e1 = exp2f(s[qs][mb][1]);
        float e2 = exp2f(s[qs][mb][2]);
        float e3 = exp2f(s[qs][mb][3]);
        unsigned p01, p23;
        asm("v_cvt_pk_bf16_f32 %0, %1, %2" : "=v"(p01) : "v"(e0), "v"(e1));
        asm("v_cvt_pk_bf16_f32 %0, %1, %2" : "=v"(p23) : "v"(e2), "v"(e3));
        uint2 pk;
        pk.x = p01;
        pk.y = p23;
        *(uint2*)&Ps[w][qs][lo][16 * mb + 4 * hi] = pk;  // m = 16mb+4hi+r, n = lo
      }
    }
    // ---- phase 3: PV + ones-MFMA row-sum; V-frags read once ----
    __builtin_amdgcn_s_setprio(1);
#pragma unroll
    for (int ks_i = 0; ks_i < 2; ks_i++) {
      short8 pa0 = *(const short8*)(&Ps[w][0][lo][32 * ks_i + 8 * hi]);
      short8 pa1 = *(const short8*)(&Ps[w][1][lo][32 * ks_i + 8 * hi]);
      accl[0] = MFMA_B16(pa0, ones, accl[0]);
      accl[1] = MFMA_B16(pa1, ones, accl[1]);
#pragma unroll
      for (int db = 0; db < 4; db++) {
        short8 vf = *(const short8*)&Vs[buf][(ks_i * 4 + db) * 512 + lane * 8];
        acc[0][db] = MFMA_B16(pa0, vf, acc[0][db]);
        acc[1][db] = MFMA_B16(pa1, vf, acc[1][db]);
      }
    }
    __builtin_amdgcn_s_setprio(0);
    __syncthreads();   // staging of buf^1 complete + all reads of buf done
    buf ^= 1;
  }

  size_t rbase = (((size_t)chunk * NB4 + b) * 4 + h) * NTOK;
#pragma unroll
  for (int qs = 0; qs < 2; qs++) {
    int nq = n0 + 128 * qs + 16 * w;
    if (lo == 0) {
#pragma unroll
      for (int r = 0; r < 4; r++)
        ml[rbase + nq + 4 * hi + r] = accl[qs][r];   // cols identical; any lo
    }
#pragma unroll
    for (int r = 0; r < 4; r++) {
      size_t row = rbase + nq + 4 * hi + r;
#pragma unroll
      for (int db = 0; db < 4; db++)
        opart[row * HD + 16 * db + lo] = f2bf(acc[qs][db][r]);
    }
  }
}

// Fused combine + output GEMM, c0-merged: block = 32 n-rows x ALL 256 c
// (Opart read exactly once). Additive combine -> As (fragment-linear,
// XOR-swizzled); wave = 64c x 32n, acc[4][2]. fp32 out.
template <int NCH>
__global__ __launch_bounds__(256, 4) void k_out(const short* __restrict__ W,
    const short* __restrict__ opart, const float* __restrict__ ml,
    const float* __restrict__ bias, float* __restrict__ outp) {
  __shared__ __align__(16) short As[8192];  // [nb(2)][i32(8)][64][8], swizzled
  int b = blockIdx.y;
  int n0 = blockIdx.x * 32;
  int t = threadIdx.x;
  int lane = t & 63, w = t >> 6;
  int lo16 = lane & 15, hi = lane >> 4;
  {
    int d8 = t & 7, h = (t >> 3) & 3, nb8 = t >> 5;   // nb8 0..7
    int i32 = 2 * h + (d8 >> 2), fhi = d8 & 3;        // fragment coords of i'
#pragma unroll
    for (int it = 0; it < 4; it++) {
      int noff = nb8 * 4 + it;                        // 0..31
      int n = n0 + noff;
      int nb = noff >> 4, flo = noff & 15;
      size_t row0 = ((size_t)b * 4 + h) * NTOK + n;   // chunk 0
      float l = ml[row0];
      float o[8];
      short8 o0 = *(const short8*)(opart + row0 * HD + d8 * 8);
#pragma unroll
      for (int j = 0; j < 8; j++) o[j] = bf2f(o0[j]);
#pragma unroll
      for (int ch = 1; ch < NCH; ch++) {
        size_t rowc = row0 + (size_t)ch * 16 * NTOK;
        l += ml[rowc];
        short8 oc = *(const short8*)(opart + rowc * HD + d8 * 8);
#pragma unroll
        for (int j = 0; j < 8; j++) o[j] += bf2f(oc[j]);
      }
      float inv = 1.0f / l;
      short8 res;
#pragma unroll
      for (int j = 0; j < 8; j++) res[j] = f2bf(o[j] * inv);
      int frag = ((nb * 8 + i32) * 64 + fhi * 16 + flo) ^ d8;  // d8==fhi|((i32&1)<<2)
      *(short8*)(As + frag * 8) = res;
    }
  }
  __syncthreads();
  f32x4 acc[4][2] = {};   // [cb][nb]
  const short* arow = W + (size_t)(64 * w + lo16) * DM + hi * 8;
#pragma unroll
  for (int ks = 0; ks < 8; ks++) {
    int sr = hi | ((ks & 1) << 2);
    short8 bbr[2];
#pragma unroll
    for (int nb = 0; nb < 2; nb++) {
      int frag = ((nb * 8 + ks) * 64 + lane) ^ sr;
      bbr[nb] = *(const short8*)(As + frag * 8);
    }
#pragma unroll
    for (int cb = 0; cb < 4; cb++) {
      short8 a = *(const short8*)(arow + (size_t)cb * 16 * DM + ks * 32);
#pragma unroll
      for (int nb = 0; nb < 2; nb++)
        acc[cb][nb] = MFMA_B16(a, bbr[nb], acc[cb][nb]);
    }
  }
#pragma unroll
  for (int cb = 0; cb < 4; cb++) {
#pragma unroll
    for (int r = 0; r < 4; r++) {
      int c = 64 * w + 16 * cb + 4 * hi + r;
      float bvv = bias[c];
#pragma unroll
      for (int nb = 0; nb < 2; nb++) {
        int n = n0 + 16 * nb + lo16;
        outp[((size_t)b * DM + c) * NTOK + n] = acc[cb][nb][r] + bvv;
      }
    }
  }
}

extern "C" void kernel_launch(void* const* d_in, const int* in_sizes, int n_in,
                              void* d_out, int out_size, void* d_ws, size_t ws_size,
                              hipStream_t stream) {
  const float* q  = (const float*)d_in[0];
  const float* k  = (const float*)d_in[1];
  const float* v  = (const float*)d_in[2];
  const float* wq = (const float*)d_in[3];
  const float* bq = (const float*)d_in[4];
  const float* wk = (const float*)d_in[5];
  const float* bk = (const float*)d_in[6];
  const float* wv = (const float*)d_in[7];
  const float* bv = (const float*)d_in[8];
  const float* wm = (const float*)d_in[9];
  const float* bm = (const float*)d_in[10];

  char* ws = (char*)d_ws;
  const size_t MB = 1024 * 1024;
  short* Qt  = (short*)(ws);              // 4MB  Q fragments
  short* Kt  = (short*)(ws + 4 * MB);     // 4MB  K fragments
  short* Vt  = (short*)(ws + 8 * MB);     // 4MB  V fragments
  short* Wbf = (short*)(ws + 12 * MB);    // 4 x 128KB
  float* ML    = (float*)(ws + 13 * MB);  // 4 chunks x 128KB row sums l
  short* Opart = (short*)(ws + 14 * MB);  // 4 chunks x 4MB bf16 partial O

  k_wpre<<<dim3(32), 256, 0, stream>>>(wq, wk, wv, wm, Wbf);
  k_proj<<<dim3(32, 12), 256, 0, stream>>>(q, k, v, Wbf, bq, bk, bv, Qt, Kt, Vt);

  if (ws_size >= 32 * MB) {
    k_attn<4><<<dim3(8, 4, 16), 512, 0, stream>>>(Qt, Kt, Vt, Opart, ML);
    k_out<4><<<dim3(64, 4), 256, 0, stream>>>(Wbf + 3 * 65536, Opart, ML, bm, (float*)d_out);
  } else {
    k_attn<1><<<dim3(8, 4, 4), 512, 0, stream>>>(Qt, Kt, Vt, Opart, ML);
    k_out<1><<<dim3(64, 4), 256, 0, stream>>>(Wbf + 3 * 65536, Opart, ML, bm, (float*)d_out);
  }

  (void)in_sizes; (void)n_in; (void)out_size; (void)ws_size;
}

// Round 11
// 69.437 us; speedup vs baseline: 1.2358x; 1.0054x over previous
//
#include <hip/hip_runtime.h>

typedef __attribute__((ext_vector_type(8))) short short8;
typedef __attribute__((ext_vector_type(4))) float f32x4;
typedef __attribute__((ext_vector_type(16))) float f32x16;

#define MFMA_B16(a, b, c) __builtin_amdgcn_mfma_f32_16x16x32_bf16((a), (b), (c), 0, 0, 0)
#define MFMA32(a, b, c) __builtin_amdgcn_mfma_f32_32x32x16_bf16((a), (b), (c), 0, 0, 0)

#define NTOK 2048
#define DM 256
#define NB4 4
#define HD 64

__device__ __forceinline__ short f2bf(float f) {
  union { float f; unsigned u; } x;
  x.f = f;
  unsigned r = x.u + 0x7fffu + ((x.u >> 16) & 1u);
  return (short)(r >> 16);
}
__device__ __forceinline__ float bf2f(short s) {
  union { unsigned u; float f; } x;
  x.u = ((unsigned)(unsigned short)s) << 16;
  return x.f;
}

// async global->LDS, 16B per lane. LDS dest = uniform base + lane*16 (HW).
__device__ __forceinline__ void gload16(const short* g, short* l) {
  __builtin_amdgcn_global_load_lds(
      (const __attribute__((address_space(1))) void*)g,
      (__attribute__((address_space(3))) void*)l, 16, 0, 0);
}

// Weights fp32->bf16; wm column-permuted to head-major:
//   W'[c][i'] = wm[c][4*(i'&63) + (i'>>6)]  (i' = 64h + d)
__global__ __launch_bounds__(256) void k_wpre(const float* __restrict__ w0,
    const float* __restrict__ w1, const float* __restrict__ w2,
    const float* __restrict__ w3, short* __restrict__ wbf) {
  int t = blockIdx.x * 256 + threadIdx.x;   // grid 32 -> 8192 threads, 32 elems each
  const float* ws4[4] = {w0, w1, w2, w3};
  int base = t * 32;
#pragma unroll
  for (int blk = 0; blk < 4; blk++) {
    int off = base + blk * 8;
    int tau = off >> 16;
    int rest = off & 65535;
    int c = rest >> 8, ip = rest & 255;
    const float* srow = ws4[tau] + (size_t)c * 256;
    short8 r;
#pragma unroll
    for (int j = 0; j < 8; j++) {
      int i2 = ip + j;
      r[j] = (tau == 3) ? f2bf(srow[4 * (i2 & 63) + (i2 >> 6)]) : f2bf(srow[i2]);
    }
    *(short8*)(wbf + off) = r;
  }
}

// Fused transpose + projection (32-wide fragment outputs for 32x32 MFMA attn).
// Block = 64 n-rows x all 256 c, one (tau,b). Stage fp32 X -> bf16 -> swizzled
// LDS As; GEMM wave = 64c x 64n (16x16 MFMA).
// Output layouts (lane32 = idx&31, hi2 = bit5):
//  Q-frag: addr(n,d) = (((bh*64 + n>>5)*4 + d>>4)*64 + (n&31) + 32*((d>>3)&1))*8 + (d&7)
//  K-frag: same formula with m=n.
//  V-frag: addr(d,m) = (((bh*128 + m>>4)*2 + d>>5)*64 + (d&31) + 32*((m>>3)&1))*8 + (m&7)
__global__ __launch_bounds__(256, 4) void k_proj(const float* __restrict__ q,
    const float* __restrict__ k, const float* __restrict__ v,
    const short* __restrict__ wbf, const float* __restrict__ bq,
    const float* __restrict__ bk, const float* __restrict__ bv,
    short* __restrict__ qt, short* __restrict__ kt, short* __restrict__ vt) {
  __shared__ __align__(16) short As[16384];  // [nb(4)][i32(8)][64][8] swizzled, 32KB
  int z = blockIdx.y, b = z & 3, tau = z >> 2;
  const float* src = ((tau == 0) ? q : (tau == 1) ? k : v) + (size_t)b * DM * NTOK;
  const short* W = wbf + (size_t)tau * 65536;
  const float* bias = (tau == 0) ? bq : (tau == 1) ? bk : bv;
  int n0 = blockIdx.x * 64;
  int t = threadIdx.x;
  // ---- stage: read fp32 (full lines), convert, swizzled LDS write ----
  {
    int nseg = t & 15, rg = t >> 4;
#pragma unroll
    for (int outer = 0; outer < 2; outer++) {
      int iG = rg + 16 * outer;       // i-granule 0..31
      const float* s0 = src + (size_t)(iG * 8) * NTOK + n0 + nseg * 4;
      float4 rows[8];
#pragma unroll
      for (int j = 0; j < 8; j++) rows[j] = *(const float4*)(s0 + (size_t)j * NTOK);
      int i32 = iG >> 2, fhi = iG & 3, s = iG & 7;
#pragma unroll
      for (int e = 0; e < 4; e++) {
        int n = nseg * 4 + e;
        int nb = n >> 4, flo = n & 15;
        short8 r;
#pragma unroll
        for (int j = 0; j < 8; j++)
          r[j] = f2bf(e == 0 ? rows[j].x : e == 1 ? rows[j].y
                                         : e == 2 ? rows[j].z : rows[j].w);
        int frag = ((nb * 8 + i32) * 64 + fhi * 16 + flo) ^ s;
        *(short8*)(As + frag * 8) = r;
      }
    }
  }
  __syncthreads();
  // ---- GEMM: wave = 64 c x 64 n, acc[cb][nb] ----
  int lane = t & 63, w = t >> 6;
  int lo = lane & 15, hi = lane >> 4;
  f32x4 acc[4][4] = {};
  const short* wrow = W + (size_t)(64 * w + lo) * DM + hi * 8;
#pragma unroll
  for (int ks = 0; ks < 8; ks++) {
    int sr = hi | ((ks & 1) << 2);
    short8 xf[4];
#pragma unroll
    for (int nb = 0; nb < 4; nb++) {
      int frag = ((nb * 8 + ks) * 64 + lane) ^ sr;
      xf[nb] = *(const short8*)(As + frag * 8);
    }
#pragma unroll
    for (int cb = 0; cb < 4; cb++) {
      short8 wf = *(const short8*)(wrow + (size_t)cb * 16 * DM + ks * 32);
      if (tau < 2) {
#pragma unroll
        for (int nb = 0; nb < 4; nb++)
          acc[cb][nb] = MFMA_B16(xf[nb], wf, acc[cb][nb]);   // col=c, row=n
      } else {
#pragma unroll
        for (int nb = 0; nb < 4; nb++)
          acc[cb][nb] = MFMA_B16(wf, xf[nb], acc[cb][nb]);   // col=n, row=c
      }
    }
  }
  if (tau < 2) {
    short* out = tau ? kt : qt;
    float scale = tau ? 1.0f : (0.125f * 1.44269504f);  // fold 1/sqrt(64), log2e into Q
#pragma unroll
    for (int cb = 0; cb < 4; cb++) {
      int c = 64 * w + 16 * cb + lo;
      float bvv = bias[c];
      int h = c & 3, d = c >> 2;
      size_t base = (size_t)(b * 4 + h) * 64;
      int dterm = (d & 31) + ((d >> 4) * 64) * 0;   // split below
#pragma unroll
      for (int nb = 0; nb < 4; nb++) {
#pragma unroll
        for (int r = 0; r < 4; r++) {
          int n = n0 + 16 * nb + 4 * hi + r;
          size_t addr = (((base + (n >> 5)) * 4 + (d >> 4)) * 64 +
                         (n & 31) + 32 * ((d >> 3) & 1)) * 8 + (d & 7);
          out[addr] = f2bf((acc[cb][nb][r] + bvv) * scale);
        }
      }
      (void)dterm;
    }
  } else {
#pragma unroll
    for (int cb = 0; cb < 4; cb++) {
#pragma unroll
      for (int r = 0; r < 4; r++) {
        int c = 64 * w + 16 * cb + 4 * hi + r;
        float bvv = bias[c];
        int h = c & 3, d = c >> 2;
        size_t base = (size_t)(b * 4 + h) * 128;
#pragma unroll
        for (int nb = 0; nb < 4; nb++) {
          int m = n0 + 16 * nb + lo;
          size_t addr = (((base + (m >> 4)) * 2 + (d >> 5)) * 64 +
                         (d & 31) + 32 * ((m >> 3) & 1)) * 8 + (m & 7);
          vt[addr] = f2bf(acc[cb][nb][r] + bvv);
        }
      }
    }
  }
}

// Flash attention, 32x32x16 MFMA, fully in-register P (no P LDS round-trip).
// 8 waves x 32 n each = 256-row Q tiles. Swapped QK^T: S col=n, row=m; P
// redistributed to PV A-operand via v_cvt_pk_bf16_f32 + v_permlane32_swap.
// No-max softmax; per-lane scalar row-sum + one shfl_xor(32) at end.
template <int SPLIT>
__global__ __launch_bounds__(512, 4) void k_attn(const short* __restrict__ qt,
    const short* __restrict__ kt, const short* __restrict__ vt,
    short* __restrict__ opart, float* __restrict__ ml) {
  __shared__ __align__(16) short Ks[2][4096];   // [m32(2)][dk(4)][lane][8]
  __shared__ __align__(16) short Vs[2][4096];   // [m16(4)][dcol(2)][lane][8]
  int z = blockIdx.z, b = z & 3, chunk = z >> 2;
  int h = blockIdx.y, n0 = blockIdx.x * 256;
  int tid = threadIdx.x;
  int lane = tid & 63, w = tid >> 6;
  int l31 = lane & 31, hi2 = lane >> 5;
  const int CH = NTOK / SPLIT;
  const int kv0 = chunk * CH;
  int bh = b * 4 + h;
  const short* Qf = qt + (size_t)bh * 131072;
  const short* Kf = kt + (size_t)bh * 131072;
  const short* Vf = vt + (size_t)bh * 131072;
  short8 qf[4];
#pragma unroll
  for (int dk = 0; dk < 4; dk++)
    qf[dk] = *(const short8*)(Qf + (((size_t)((n0 >> 5) + w) * 4 + dk) * 64 + lane) * 8);
  f32x16 acc[2] = {};
  float lacc = 0.0f;

  int nt = CH >> 6, buf = 0;
  gload16(Kf + (size_t)(kv0 >> 5) * 2048 + tid * 8, &Ks[0][tid * 8]);
  gload16(Vf + (size_t)(kv0 >> 4) * 1024 + tid * 8, &Vs[0][tid * 8]);
  __syncthreads();   // vmcnt drain -> staged data visible

  for (int t = 0; t < nt; t++) {
    int m0 = kv0 + (t << 6);
    if (t + 1 < nt) {
      gload16(Kf + (size_t)((m0 + 64) >> 5) * 2048 + tid * 8, &Ks[buf ^ 1][tid * 8]);
      gload16(Vf + (size_t)((m0 + 64) >> 4) * 1024 + tid * 8, &Vs[buf ^ 1][tid * 8]);
    }
#pragma unroll
    for (int mb2 = 0; mb2 < 2; mb2++) {
      // ---- QK^T: S[m 32][n 32], chained over 4 k-slices of d ----
      f32x16 s = {};
      __builtin_amdgcn_s_setprio(1);
#pragma unroll
      for (int dk = 0; dk < 4; dk++) {
        short8 kf = *(const short8*)&Ks[buf][(mb2 * 4 + dk) * 512 + lane * 8];
        s = MFMA32(kf, qf[dk], s);
      }
      __builtin_amdgcn_s_setprio(0);
      // ---- softmax + in-register P->A redistribution + PV ----
#pragma unroll
      for (int ks = 0; ks < 2; ks++) {
        float e0 = exp2f(s[ks * 8 + 0]), e1 = exp2f(s[ks * 8 + 1]);
        float e2 = exp2f(s[ks * 8 + 2]), e3 = exp2f(s[ks * 8 + 3]);
        float e4 = exp2f(s[ks * 8 + 4]), e5 = exp2f(s[ks * 8 + 5]);
        float e6 = exp2f(s[ks * 8 + 6]), e7 = exp2f(s[ks * 8 + 7]);
        lacc += ((e0 + e1) + (e2 + e3)) + ((e4 + e5) + (e6 + e7));
        unsigned A, B, C2, D2;
        asm("v_cvt_pk_bf16_f32 %0, %1, %2" : "=v"(A) : "v"(e0), "v"(e1));
        asm("v_cvt_pk_bf16_f32 %0, %1, %2" : "=v"(C2) : "v"(e2), "v"(e3));
        asm("v_cvt_pk_bf16_f32 %0, %1, %2" : "=v"(B) : "v"(e4), "v"(e5));
        asm("v_cvt_pk_bf16_f32 %0, %1, %2" : "=v"(D2) : "v"(e6), "v"(e7));
        // swap: A' = (A_lo, B_lo) = pa w0;  B' = (A_hi, B_hi) = pa w2
        asm("v_permlane32_swap_b32 %0, %1" : "+v"(A), "+v"(B));
        asm("v_permlane32_swap_b32 %0, %1" : "+v"(C2), "+v"(D2));
        union { unsigned u[4]; short8 v8; } pu;
        pu.u[0] = A; pu.u[1] = C2; pu.u[2] = B; pu.u[3] = D2;
        __builtin_amdgcn_s_setprio(1);
#pragma unroll
        for (int dcol = 0; dcol < 2; dcol++) {
          short8 vf = *(const short8*)&Vs[buf][((mb2 * 2 + ks) * 2 + dcol) * 512 + lane * 8];
          acc[dcol] = MFMA32(pu.v8, vf, acc[dcol]);
        }
        __builtin_amdgcn_s_setprio(0);
      }
    }
    __syncthreads();   // staging of buf^1 complete + all reads of buf done
    buf ^= 1;
  }

  // row-sum: combine the two lane-halves (same n at lane and lane^32)
  float l = lacc + __shfl_xor(lacc, 32);
  size_t rbase = (((size_t)chunk * NB4 + b) * 4 + h) * NTOK;
  if (lane < 32) ml[rbase + n0 + 32 * w + lane] = l;
#pragma unroll
  for (int r = 0; r < 16; r++) {
    int n = n0 + 32 * w + (r & 3) + 8 * (r >> 2) + 4 * hi2;
#pragma unroll
    for (int dcol = 0; dcol < 2; dcol++)
      opart[(rbase + n) * HD + dcol * 32 + l31] = f2bf(acc[dcol][r]);
  }
}

// Fused combine + output GEMM, c0-merged: block = 32 n-rows x ALL 256 c.
// Additive combine -> As (fragment-linear, XOR-swizzled); wave = 64c x 32n.
template <int NCH>
__global__ __launch_bounds__(256, 4) void k_out(const short* __restrict__ W,
    const short* __restrict__ opart, const float* __restrict__ ml,
    const float* __restrict__ bias, float* __restrict__ outp) {
  __shared__ __align__(16) short As[8192];  // [nb(2)][i32(8)][64][8], swizzled
  int b = blockIdx.y;
  int n0 = blockIdx.x * 32;
  int t = threadIdx.x;
  int lane = t & 63, w = t >> 6;
  int lo16 = lane & 15, hi = lane >> 4;
  {
    int d8 = t & 7, h = (t >> 3) & 3, nb8 = t >> 5;   // nb8 0..7
    int i32 = 2 * h + (d8 >> 2), fhi = d8 & 3;        // fragment coords of i'
#pragma unroll
    for (int it = 0; it < 4; it++) {
      int noff = nb8 * 4 + it;                        // 0..31
      int n = n0 + noff;
      int nb = noff >> 4, flo = noff & 15;
      size_t row0 = ((size_t)b * 4 + h) * NTOK + n;   // chunk 0
      float l = ml[row0];
      float o[8];
      short8 o0 = *(const short8*)(opart + row0 * HD + d8 * 8);
#pragma unroll
      for (int j = 0; j < 8; j++) o[j] = bf2f(o0[j]);
#pragma unroll
      for (int ch = 1; ch < NCH; ch++) {
        size_t rowc = row0 + (size_t)ch * 16 * NTOK;
        l += ml[rowc];
        short8 oc = *(const short8*)(opart + rowc * HD + d8 * 8);
#pragma unroll
        for (int j = 0; j < 8; j++) o[j] += bf2f(oc[j]);
      }
      float inv = 1.0f / l;
      short8 res;
#pragma unroll
      for (int j = 0; j < 8; j++) res[j] = f2bf(o[j] * inv);
      int frag = ((nb * 8 + i32) * 64 + fhi * 16 + flo) ^ d8;  // d8==fhi|((i32&1)<<2)
      *(short8*)(As + frag * 8) = res;
    }
  }
  __syncthreads();
  f32x4 acc[4][2] = {};   // [cb][nb]
  const short* arow = W + (size_t)(64 * w + lo16) * DM + hi * 8;
#pragma unroll
  for (int ks = 0; ks < 8; ks++) {
    int sr = hi | ((ks & 1) << 2);
    short8 bbr[2];
#pragma unroll
    for (int nb = 0; nb < 2; nb++) {
      int frag = ((nb * 8 + ks) * 64 + lane) ^ sr;
      bbr[nb] = *(const short8*)(As + frag * 8);
    }
#pragma unroll
    for (int cb = 0; cb < 4; cb++) {
      short8 a = *(const short8*)(arow + (size_t)cb * 16 * DM + ks * 32);
#pragma unroll
      for (int nb = 0; nb < 2; nb++)
        acc[cb][nb] = MFMA_B16(a, bbr[nb], acc[cb][nb]);
    }
  }
#pragma unroll
  for (int cb = 0; cb < 4; cb++) {
#pragma unroll
    for (int r = 0; r < 4; r++) {
      int c = 64 * w + 16 * cb + 4 * hi + r;
      float bvv = bias[c];
#pragma unroll
      for (int nb = 0; nb < 2; nb++) {
        int n = n0 + 16 * nb + lo16;
        outp[((size_t)b * DM + c) * NTOK + n] = acc[cb][nb][r] + bvv;
      }
    }
  }
}

extern "C" void kernel_launch(void* const* d_in, const int* in_sizes, int n_in,
                              void* d_out, int out_size, void* d_ws, size_t ws_size,
                              hipStream_t stream) {
  const float* q  = (const float*)d_in[0];
  const float* k  = (const float*)d_in[1];
  const float* v  = (const float*)d_in[2];
  const float* wq = (const float*)d_in[3];
  const float* bq = (const float*)d_in[4];
  const float* wk = (const float*)d_in[5];
  const float* bk = (const float*)d_in[6];
  const float* wv = (const float*)d_in[7];
  const float* bv = (const float*)d_in[8];
  const float* wm = (const float*)d_in[9];
  const float* bm = (const float*)d_in[10];

  char* ws = (char*)d_ws;
  const size_t MB = 1024 * 1024;
  short* Qt  = (short*)(ws);              // 4MB  Q fragments (32-wide)
  short* Kt  = (short*)(ws + 4 * MB);     // 4MB  K fragments
  short* Vt  = (short*)(ws + 8 * MB);     // 4MB  V fragments
  short* Wbf = (short*)(ws + 12 * MB);    // 4 x 128KB
  float* ML    = (float*)(ws + 13 * MB);  // 4 chunks x 128KB row sums l
  short* Opart = (short*)(ws + 14 * MB);  // 4 chunks x 4MB bf16 partial O

  k_wpre<<<dim3(32), 256, 0, stream>>>(wq, wk, wv, wm, Wbf);
  k_proj<<<dim3(32, 12), 256, 0, stream>>>(q, k, v, Wbf, bq, bk, bv, Qt, Kt, Vt);

  if (ws_size >= 32 * MB) {
    k_attn<4><<<dim3(8, 4, 16), 512, 0, stream>>>(Qt, Kt, Vt, Opart, ML);
    k_out<4><<<dim3(64, 4), 256, 0, stream>>>(Wbf + 3 * 65536, Opart, ML, bm, (float*)d_out);
  } else {
    k_attn<1><<<dim3(8, 4, 4), 512, 0, stream>>>(Qt, Kt, Vt, Opart, ML);
    k_out<1><<<dim3(64, 4), 256, 0, stream>>>(Wbf + 3 * 65536, Opart, ML, bm, (float*)d_out);
  }

  (void)in_sizes; (void)n_in; (void)out_size; (void)ws_size;
}

// Round 12
// 68.881 us; speedup vs baseline: 1.2458x; 1.0081x over previous
//
#include <hip/hip_runtime.h>

typedef __attribute__((ext_vector_type(8))) short short8;
typedef __attribute__((ext_vector_type(4))) float f32x4;
typedef __attribute__((ext_vector_type(16))) float f32x16;

#define MFMA_B16(a, b, c) __builtin_amdgcn_mfma_f32_16x16x32_bf16((a), (b), (c), 0, 0, 0)
#define MFMA32(a, b, c) __builtin_amdgcn_mfma_f32_32x32x16_bf16((a), (b), (c), 0, 0, 0)

#define NTOK 2048
#define DM 256
#define NB4 4
#define HD 64

__device__ __forceinline__ short f2bf(float f) {
  union { float f; unsigned u; } x;
  x.f = f;
  unsigned r = x.u + 0x7fffu + ((x.u >> 16) & 1u);
  return (short)(r >> 16);
}
__device__ __forceinline__ float bf2f(short s) {
  union { unsigned u; float f; } x;
  x.u = ((unsigned)(unsigned short)s) << 16;
  return x.f;
}

// async global->LDS, 16B per lane. LDS dest = uniform base + lane*16 (HW).
__device__ __forceinline__ void gload16(const short* g, short* l) {
  __builtin_amdgcn_global_load_lds(
      (const __attribute__((address_space(1))) void*)g,
      (__attribute__((address_space(3))) void*)l, 16, 0, 0);
}

// Weights fp32->bf16; wm column-permuted to head-major:
//   W'[c][i'] = wm[c][4*(i'&63) + (i'>>6)]  (i' = 64h + d)
__global__ __launch_bounds__(256) void k_wpre(const float* __restrict__ w0,
    const float* __restrict__ w1, const float* __restrict__ w2,
    const float* __restrict__ w3, short* __restrict__ wbf) {
  int t = blockIdx.x * 256 + threadIdx.x;   // grid 32 -> 8192 threads, 32 elems each
  const float* ws4[4] = {w0, w1, w2, w3};
  int base = t * 32;
#pragma unroll
  for (int blk = 0; blk < 4; blk++) {
    int off = base + blk * 8;
    int tau = off >> 16;
    int rest = off & 65535;
    int c = rest >> 8, ip = rest & 255;
    const float* srow = ws4[tau] + (size_t)c * 256;
    short8 r;
#pragma unroll
    for (int j = 0; j < 8; j++) {
      int i2 = ip + j;
      r[j] = (tau == 3) ? f2bf(srow[4 * (i2 & 63) + (i2 >> 6)]) : f2bf(srow[i2]);
    }
    *(short8*)(wbf + off) = r;
  }
}

// Fused transpose + projection (32-wide fragment outputs for 32x32 MFMA attn).
// Block = 64 n-rows x all 256 c, one (tau,b). Stage fp32 X -> bf16 -> swizzled
// LDS As; GEMM wave = 64c x 64n (16x16 MFMA).
// Output layouts (lane32 = idx&31, hi2 = bit5):
//  Q-frag: addr(n,d) = (((bh*64 + n>>5)*4 + d>>4)*64 + (n&31) + 32*((d>>3)&1))*8 + (d&7)
//  K-frag: same formula with m=n.
//  V-frag: addr(d,m) = (((bh*128 + m>>4)*2 + d>>5)*64 + (d&31) + 32*((m>>3)&1))*8 + (m&7)
__global__ __launch_bounds__(256, 4) void k_proj(const float* __restrict__ q,
    const float* __restrict__ k, const float* __restrict__ v,
    const short* __restrict__ wbf, const float* __restrict__ bq,
    const float* __restrict__ bk, const float* __restrict__ bv,
    short* __restrict__ qt, short* __restrict__ kt, short* __restrict__ vt) {
  __shared__ __align__(16) short As[16384];  // [nb(4)][i32(8)][64][8] swizzled, 32KB
  int z = blockIdx.y, b = z & 3, tau = z >> 2;
  const float* src = ((tau == 0) ? q : (tau == 1) ? k : v) + (size_t)b * DM * NTOK;
  const short* W = wbf + (size_t)tau * 65536;
  const float* bias = (tau == 0) ? bq : (tau == 1) ? bk : bv;
  int n0 = blockIdx.x * 64;
  int t = threadIdx.x;
  // ---- stage: read fp32 (full lines), convert, swizzled LDS write ----
  {
    int nseg = t & 15, rg = t >> 4;
#pragma unroll
    for (int outer = 0; outer < 2; outer++) {
      int iG = rg + 16 * outer;       // i-granule 0..31
      const float* s0 = src + (size_t)(iG * 8) * NTOK + n0 + nseg * 4;
      float4 rows[8];
#pragma unroll
      for (int j = 0; j < 8; j++) rows[j] = *(const float4*)(s0 + (size_t)j * NTOK);
      int i32 = iG >> 2, fhi = iG & 3, s = iG & 7;
#pragma unroll
      for (int e = 0; e < 4; e++) {
        int n = nseg * 4 + e;
        int nb = n >> 4, flo = n & 15;
        short8 r;
#pragma unroll
        for (int j = 0; j < 8; j++)
          r[j] = f2bf(e == 0 ? rows[j].x : e == 1 ? rows[j].y
                                         : e == 2 ? rows[j].z : rows[j].w);
        int frag = ((nb * 8 + i32) * 64 + fhi * 16 + flo) ^ s;
        *(short8*)(As + frag * 8) = r;
      }
    }
  }
  __syncthreads();
  // ---- GEMM: wave = 64 c x 64 n, acc[cb][nb] ----
  int lane = t & 63, w = t >> 6;
  int lo = lane & 15, hi = lane >> 4;
  f32x4 acc[4][4] = {};
  const short* wrow = W + (size_t)(64 * w + lo) * DM + hi * 8;
#pragma unroll
  for (int ks = 0; ks < 8; ks++) {
    int sr = hi | ((ks & 1) << 2);
    short8 xf[4];
#pragma unroll
    for (int nb = 0; nb < 4; nb++) {
      int frag = ((nb * 8 + ks) * 64 + lane) ^ sr;
      xf[nb] = *(const short8*)(As + frag * 8);
    }
#pragma unroll
    for (int cb = 0; cb < 4; cb++) {
      short8 wf = *(const short8*)(wrow + (size_t)cb * 16 * DM + ks * 32);
      if (tau < 2) {
#pragma unroll
        for (int nb = 0; nb < 4; nb++)
          acc[cb][nb] = MFMA_B16(xf[nb], wf, acc[cb][nb]);   // col=c, row=n
      } else {
#pragma unroll
        for (int nb = 0; nb < 4; nb++)
          acc[cb][nb] = MFMA_B16(wf, xf[nb], acc[cb][nb]);   // col=n, row=c
      }
    }
  }
  if (tau < 2) {
    short* out = tau ? kt : qt;
    float scale = tau ? 1.0f : (0.125f * 1.44269504f);  // fold 1/sqrt(64), log2e into Q
#pragma unroll
    for (int cb = 0; cb < 4; cb++) {
      int c = 64 * w + 16 * cb + lo;
      float bvv = bias[c];
      int h = c & 3, d = c >> 2;
      size_t base = (size_t)(b * 4 + h) * 64;
#pragma unroll
      for (int nb = 0; nb < 4; nb++) {
#pragma unroll
        for (int r = 0; r < 4; r++) {
          int n = n0 + 16 * nb + 4 * hi + r;
          size_t addr = (((base + (n >> 5)) * 4 + (d >> 4)) * 64 +
                         (n & 31) + 32 * ((d >> 3) & 1)) * 8 + (d & 7);
          out[addr] = f2bf((acc[cb][nb][r] + bvv) * scale);
        }
      }
    }
  } else {
#pragma unroll
    for (int cb = 0; cb < 4; cb++) {
#pragma unroll
      for (int r = 0; r < 4; r++) {
        int c = 64 * w + 16 * cb + 4 * hi + r;
        float bvv = bias[c];
        int h = c & 3, d = c >> 2;
        size_t base = (size_t)(b * 4 + h) * 128;
#pragma unroll
        for (int nb = 0; nb < 4; nb++) {
          int m = n0 + 16 * nb + lo;
          size_t addr = (((base + (m >> 4)) * 2 + (d >> 5)) * 64 +
                         (d & 31) + 32 * ((m >> 3) & 1)) * 8 + (m & 7);
          vt[addr] = f2bf(acc[cb][nb][r] + bvv);
        }
      }
    }
  }
}

// Flash attention, 32x32x16 MFMA, fully in-register P. 8 waves x 32 n = 256-row
// Q tiles. Swapped QK^T; P redistributed via v_cvt_pk_bf16_f32 + permlane32_swap.
// No-max softmax; per-lane row-sum + one shfl_xor(32).
// SPLIT==4: 1-D grid 512 with XCD-aware decode (T1): dispatch maps bid%8->XCD,
// so we place the 8 q-tile blocks of each (b,h,chunk) group at bids with equal
// bid%8 -> same XCD -> K/V chunk staged once into that XCD's L2, 7/8 of the
// staging reads become L2 hits (bijective: bid <-> (xcd,slot)).
template <int SPLIT>
__global__ __launch_bounds__(512, 4) void k_attn(const short* __restrict__ qt,
    const short* __restrict__ kt, const short* __restrict__ vt,
    short* __restrict__ opart, float* __restrict__ ml) {
  __shared__ __align__(16) short Ks[2][4096];   // [m32(2)][dk(4)][lane][8]
  __shared__ __align__(16) short Vs[2][4096];   // [m16(4)][dcol(2)][lane][8]
  int b, h, chunk, n0;
  if (SPLIT == 4) {
    int bid = blockIdx.x;
    int xcd = bid & 7, slot = bid >> 3;
    int g = xcd + 8 * (slot >> 3);    // group 0..63, g%8 == xcd
    n0 = (slot & 7) * 256;            // q-tile within group
    h = g & 3;
    int zz = g >> 2;                  // 0..15
    b = zz & 3;
    chunk = zz >> 2;
  } else {
    b = blockIdx.z & 3; chunk = 0; h = blockIdx.y; n0 = blockIdx.x * 256;
  }
  int tid = threadIdx.x;
  int lane = tid & 63, w = tid >> 6;
  int l31 = lane & 31, hi2 = lane >> 5;
  const int CH = NTOK / SPLIT;
  const int kv0 = chunk * CH;
  int bh = b * 4 + h;
  const short* Qf = qt + (size_t)bh * 131072;
  const short* Kf = kt + (size_t)bh * 131072;
  const short* Vf = vt + (size_t)bh * 131072;
  short8 qf[4];
#pragma unroll
  for (int dk = 0; dk < 4; dk++)
    qf[dk] = *(const short8*)(Qf + (((size_t)((n0 >> 5) + w) * 4 + dk) * 64 + lane) * 8);
  f32x16 acc[2] = {};
  float lacc = 0.0f;

  int nt = CH >> 6, buf = 0;
  gload16(Kf + (size_t)(kv0 >> 5) * 2048 + tid * 8, &Ks[0][tid * 8]);
  gload16(Vf + (size_t)(kv0 >> 4) * 1024 + tid * 8, &Vs[0][tid * 8]);
  __syncthreads();   // vmcnt drain -> staged data visible

  for (int t = 0; t < nt; t++) {
    int m0 = kv0 + (t << 6);
    if (t + 1 < nt) {
      gload16(Kf + (size_t)((m0 + 64) >> 5) * 2048 + tid * 8, &Ks[buf ^ 1][tid * 8]);
      gload16(Vf + (size_t)((m0 + 64) >> 4) * 1024 + tid * 8, &Vs[buf ^ 1][tid * 8]);
    }
#pragma unroll
    for (int mb2 = 0; mb2 < 2; mb2++) {
      // ---- QK^T: S[m 32][n 32], chained over 4 k-slices of d ----
      f32x16 s = {};
      __builtin_amdgcn_s_setprio(1);
#pragma unroll
      for (int dk = 0; dk < 4; dk++) {
        short8 kf = *(const short8*)&Ks[buf][(mb2 * 4 + dk) * 512 + lane * 8];
        s = MFMA32(kf, qf[dk], s);
      }
      __builtin_amdgcn_s_setprio(0);
      // ---- softmax + in-register P->A redistribution + PV ----
#pragma unroll
      for (int ks = 0; ks < 2; ks++) {
        float e0 = exp2f(s[ks * 8 + 0]), e1 = exp2f(s[ks * 8 + 1]);
        float e2 = exp2f(s[ks * 8 + 2]), e3 = exp2f(s[ks * 8 + 3]);
        float e4 = exp2f(s[ks * 8 + 4]), e5 = exp2f(s[ks * 8 + 5]);
        float e6 = exp2f(s[ks * 8 + 6]), e7 = exp2f(s[ks * 8 + 7]);
        lacc += ((e0 + e1) + (e2 + e3)) + ((e4 + e5) + (e6 + e7));
        unsigned A, B, C2, D2;
        asm("v_cvt_pk_bf16_f32 %0, %1, %2" : "=v"(A) : "v"(e0), "v"(e1));
        asm("v_cvt_pk_bf16_f32 %0, %1, %2" : "=v"(C2) : "v"(e2), "v"(e3));
        asm("v_cvt_pk_bf16_f32 %0, %1, %2" : "=v"(B) : "v"(e4), "v"(e5));
        asm("v_cvt_pk_bf16_f32 %0, %1, %2" : "=v"(D2) : "v"(e6), "v"(e7));
        // swap: A' = (A_lo, B_lo) = pa w0;  B' = (A_hi, B_hi) = pa w2
        asm("v_permlane32_swap_b32 %0, %1" : "+v"(A), "+v"(B));
        asm("v_permlane32_swap_b32 %0, %1" : "+v"(C2), "+v"(D2));
        union { unsigned u[4]; short8 v8; } pu;
        pu.u[0] = A; pu.u[1] = C2; pu.u[2] = B; pu.u[3] = D2;
        __builtin_amdgcn_s_setprio(1);
#pragma unroll
        for (int dcol = 0; dcol < 2; dcol++) {
          short8 vf = *(const short8*)&Vs[buf][((mb2 * 2 + ks) * 2 + dcol) * 512 + lane * 8];
          acc[dcol] = MFMA32(pu.v8, vf, acc[dcol]);
        }
        __builtin_amdgcn_s_setprio(0);
      }
    }
    __syncthreads();   // staging of buf^1 complete + all reads of buf done
    buf ^= 1;
  }

  // row-sum: combine the two lane-halves (same n at lane and lane^32)
  float l = lacc + __shfl_xor(lacc, 32);
  size_t rbase = (((size_t)chunk * NB4 + b) * 4 + h) * NTOK;
  if (lane < 32) ml[rbase + n0 + 32 * w + lane] = l;
#pragma unroll
  for (int r = 0; r < 16; r++) {
    int n = n0 + 32 * w + (r & 3) + 8 * (r >> 2) + 4 * hi2;
#pragma unroll
    for (int dcol = 0; dcol < 2; dcol++)
      opart[(rbase + n) * HD + dcol * 32 + l31] = f2bf(acc[dcol][r]);
  }
}

// Fused combine + output GEMM, c0-merged: block = 32 n-rows x ALL 256 c.
// Additive combine -> As (fragment-linear, XOR-swizzled); wave = 64c x 32n.
template <int NCH>
__global__ __launch_bounds__(256, 4) void k_out(const short* __restrict__ W,
    const short* __restrict__ opart, const float* __restrict__ ml,
    const float* __restrict__ bias, float* __restrict__ outp) {
  __shared__ __align__(16) short As[8192];  // [nb(2)][i32(8)][64][8], swizzled
  int b = blockIdx.y;
  int n0 = blockIdx.x * 32;
  int t = threadIdx.x;
  int lane = t & 63, w = t >> 6;
  int lo16 = lane & 15, hi = lane >> 4;
  {
    int d8 = t & 7, h = (t >> 3) & 3, nb8 = t >> 5;   // nb8 0..7
    int i32 = 2 * h + (d8 >> 2), fhi = d8 & 3;        // fragment coords of i'
#pragma unroll
    for (int it = 0; it < 4; it++) {
      int noff = nb8 * 4 + it;                        // 0..31
      int n = n0 + noff;
      int nb = noff >> 4, flo = noff & 15;
      size_t row0 = ((size_t)b * 4 + h) * NTOK + n;   // chunk 0
      float l = ml[row0];
      float o[8];
      short8 o0 = *(const short8*)(opart + row0 * HD + d8 * 8);
#pragma unroll
      for (int j = 0; j < 8; j++) o[j] = bf2f(o0[j]);
#pragma unroll
      for (int ch = 1; ch < NCH; ch++) {
        size_t rowc = row0 + (size_t)ch * 16 * NTOK;
        l += ml[rowc];
        short8 oc = *(const short8*)(opart + rowc * HD + d8 * 8);
#pragma unroll
        for (int j = 0; j < 8; j++) o[j] += bf2f(oc[j]);
      }
      float inv = 1.0f / l;
      short8 res;
#pragma unroll
      for (int j = 0; j < 8; j++) res[j] = f2bf(o[j] * inv);
      int frag = ((nb * 8 + i32) * 64 + fhi * 16 + flo) ^ d8;  // d8==fhi|((i32&1)<<2)
      *(short8*)(As + frag * 8) = res;
    }
  }
  __syncthreads();
  f32x4 acc[4][2] = {};   // [cb][nb]
  const short* arow = W + (size_t)(64 * w + lo16) * DM + hi * 8;
#pragma unroll
  for (int ks = 0; ks < 8; ks++) {
    int sr = hi | ((ks & 1) << 2);
    short8 bbr[2];
#pragma unroll
    for (int nb = 0; nb < 2; nb++) {
      int frag = ((nb * 8 + ks) * 64 + lane) ^ sr;
      bbr[nb] = *(const short8*)(As + frag * 8);
    }
#pragma unroll
    for (int cb = 0; cb < 4; cb++) {
      short8 a = *(const short8*)(arow + (size_t)cb * 16 * DM + ks * 32);
#pragma unroll
      for (int nb = 0; nb < 2; nb++)
        acc[cb][nb] = MFMA_B16(a, bbr[nb], acc[cb][nb]);
    }
  }
#pragma unroll
  for (int cb = 0; cb < 4; cb++) {
#pragma unroll
    for (int r = 0; r < 4; r++) {
      int c = 64 * w + 16 * cb + 4 * hi + r;
      float bvv = bias[c];
#pragma unroll
      for (int nb = 0; nb < 2; nb++) {
        int n = n0 + 16 * nb + lo16;
        outp[((size_t)b * DM + c) * NTOK + n] = acc[cb][nb][r] + bvv;
      }
    }
  }
}

extern "C" void kernel_launch(void* const* d_in, const int* in_sizes, int n_in,
                              void* d_out, int out_size, void* d_ws, size_t ws_size,
                              hipStream_t stream) {
  const float* q  = (const float*)d_in[0];
  const float* k  = (const float*)d_in[1];
  const float* v  = (const float*)d_in[2];
  const float* wq = (const float*)d_in[3];
  const float* bq = (const float*)d_in[4];
  const float* wk = (const float*)d_in[5];
  const float* bk = (const float*)d_in[6];
  const float* wv = (const float*)d_in[7];
  const float* bv = (const float*)d_in[8];
  const float* wm = (const float*)d_in[9];
  const float* bm = (const float*)d_in[10];

  char* ws = (char*)d_ws;
  const size_t MB = 1024 * 1024;
  short* Qt  = (short*)(ws);              // 4MB  Q fragments (32-wide)
  short* Kt  = (short*)(ws + 4 * MB);     // 4MB  K fragments
  short* Vt  = (short*)(ws + 8 * MB);     // 4MB  V fragments
  short* Wbf = (short*)(ws + 12 * MB);    // 4 x 128KB
  float* ML    = (float*)(ws + 13 * MB);  // 4 chunks x 128KB row sums l
  short* Opart = (short*)(ws + 14 * MB);  // 4 chunks x 4MB bf16 partial O

  k_wpre<<<dim3(32), 256, 0, stream>>>(wq, wk, wv, wm, Wbf);
  k_proj<<<dim3(32, 12), 256, 0, stream>>>(q, k, v, Wbf, bq, bk, bv, Qt, Kt, Vt);

  if (ws_size >= 32 * MB) {
    k_attn<4><<<dim3(512), 512, 0, stream>>>(Qt, Kt, Vt, Opart, ML);
    k_out<4><<<dim3(64, 4), 256, 0, stream>>>(Wbf + 3 * 65536, Opart, ML, bm, (float*)d_out);
  } else {
    k_attn<1><<<dim3(8, 4, 4), 512, 0, stream>>>(Qt, Kt, Vt, Opart, ML);
    k_out<1><<<dim3(64, 4), 256, 0, stream>>>(Wbf + 3 * 65536, Opart, ML, bm, (float*)d_out);
  }

  (void)in_sizes; (void)n_in; (void)out_size; (void)ws_size;
}

// Round 13
// 68.218 us; speedup vs baseline: 1.2579x; 1.0097x over previous
//
#include <hip/hip_runtime.h>

typedef __attribute__((ext_vector_type(8))) short short8;
typedef __attribute__((ext_vector_type(4))) float f32x4;
typedef __attribute__((ext_vector_type(16))) float f32x16;

#define MFMA_B16(a, b, c) __builtin_amdgcn_mfma_f32_16x16x32_bf16((a), (b), (c), 0, 0, 0)
#define MFMA32(a, b, c) __builtin_amdgcn_mfma_f32_32x32x16_bf16((a), (b), (c), 0, 0, 0)

#define NTOK 2048
#define DM 256
#define NB4 4
#define HD 64

__device__ __forceinline__ short f2bf(float f) {
  union { float f; unsigned u; } x;
  x.f = f;
  unsigned r = x.u + 0x7fffu + ((x.u >> 16) & 1u);
  return (short)(r >> 16);
}
__device__ __forceinline__ float bf2f(short s) {
  union { unsigned u; float f; } x;
  x.u = ((unsigned)(unsigned short)s) << 16;
  return x.f;
}

// async global->LDS, 16B per lane. LDS dest = uniform base + lane*16 (HW).
__device__ __forceinline__ void gload16(const short* g, short* l) {
  __builtin_amdgcn_global_load_lds(
      (const __attribute__((address_space(1))) void*)g,
      (__attribute__((address_space(3))) void*)l, 16, 0, 0);
}

// Weights fp32->bf16; wm column-permuted to head-major:
//   W'[c][i'] = wm[c][4*(i'&63) + (i'>>6)]  (i' = 64h + d)
__global__ __launch_bounds__(256) void k_wpre(const float* __restrict__ w0,
    const float* __restrict__ w1, const float* __restrict__ w2,
    const float* __restrict__ w3, short* __restrict__ wbf) {
  int t = blockIdx.x * 256 + threadIdx.x;   // grid 32 -> 8192 threads, 32 elems each
  const float* ws4[4] = {w0, w1, w2, w3};
  int base = t * 32;
#pragma unroll
  for (int blk = 0; blk < 4; blk++) {
    int off = base + blk * 8;
    int tau = off >> 16;
    int rest = off & 65535;
    int c = rest >> 8, ip = rest & 255;
    const float* srow = ws4[tau] + (size_t)c * 256;
    short8 r;
#pragma unroll
    for (int j = 0; j < 8; j++) {
      int i2 = ip + j;
      r[j] = (tau == 3) ? f2bf(srow[4 * (i2 & 63) + (i2 >> 6)]) : f2bf(srow[i2]);
    }
    *(short8*)(wbf + off) = r;
  }
}

// Fused transpose + projection (32-wide fragment outputs for 32x32 MFMA attn).
// Block = 64 n-rows x all 256 c, one (tau,b). Stage fp32 X -> bf16 -> swizzled
// LDS As; GEMM wave = 64c x 64n (16x16 MFMA).
// Output layouts (lane32 = idx&31, hi2 = bit5):
//  Q-frag: addr(n,d) = (((bh*64 + n>>5)*4 + d>>4)*64 + (n&31) + 32*((d>>3)&1))*8 + (d&7)
//  K-frag: same formula with m=n.
//  V-frag: addr(d,m) = (((bh*128 + m>>4)*2 + d>>5)*64 + (d&31) + 32*((m>>3)&1))*8 + (m&7)
__global__ __launch_bounds__(256, 4) void k_proj(const float* __restrict__ q,
    const float* __restrict__ k, const float* __restrict__ v,
    const short* __restrict__ wbf, const float* __restrict__ bq,
    const float* __restrict__ bk, const float* __restrict__ bv,
    short* __restrict__ qt, short* __restrict__ kt, short* __restrict__ vt) {
  __shared__ __align__(16) short As[16384];  // [nb(4)][i32(8)][64][8] swizzled, 32KB
  int z = blockIdx.y, b = z & 3, tau = z >> 2;
  const float* src = ((tau == 0) ? q : (tau == 1) ? k : v) + (size_t)b * DM * NTOK;
  const short* W = wbf + (size_t)tau * 65536;
  const float* bias = (tau == 0) ? bq : (tau == 1) ? bk : bv;
  int n0 = blockIdx.x * 64;
  int t = threadIdx.x;
  // ---- stage: read fp32 (full lines), convert, swizzled LDS write ----
  {
    int nseg = t & 15, rg = t >> 4;
#pragma unroll
    for (int outer = 0; outer < 2; outer++) {
      int iG = rg + 16 * outer;       // i-granule 0..31
      const float* s0 = src + (size_t)(iG * 8) * NTOK + n0 + nseg * 4;
      float4 rows[8];
#pragma unroll
      for (int j = 0; j < 8; j++) rows[j] = *(const float4*)(s0 + (size_t)j * NTOK);
      int i32 = iG >> 2, fhi = iG & 3, s = iG & 7;
#pragma unroll
      for (int e = 0; e < 4; e++) {
        int n = nseg * 4 + e;
        int nb = n >> 4, flo = n & 15;
        short8 r;
#pragma unroll
        for (int j = 0; j < 8; j++)
          r[j] = f2bf(e == 0 ? rows[j].x : e == 1 ? rows[j].y
                                         : e == 2 ? rows[j].z : rows[j].w);
        int frag = ((nb * 8 + i32) * 64 + fhi * 16 + flo) ^ s;
        *(short8*)(As + frag * 8) = r;
      }
    }
  }
  __syncthreads();
  // ---- GEMM: wave = 64 c x 64 n, acc[cb][nb] ----
  int lane = t & 63, w = t >> 6;
  int lo = lane & 15, hi = lane >> 4;
  f32x4 acc[4][4] = {};
  const short* wrow = W + (size_t)(64 * w + lo) * DM + hi * 8;
#pragma unroll
  for (int ks = 0; ks < 8; ks++) {
    int sr = hi | ((ks & 1) << 2);
    short8 xf[4];
#pragma unroll
    for (int nb = 0; nb < 4; nb++) {
      int frag = ((nb * 8 + ks) * 64 + lane) ^ sr;
      xf[nb] = *(const short8*)(As + frag * 8);
    }
#pragma unroll
    for (int cb = 0; cb < 4; cb++) {
      short8 wf = *(const short8*)(wrow + (size_t)cb * 16 * DM + ks * 32);
      if (tau < 2) {
#pragma unroll
        for (int nb = 0; nb < 4; nb++)
          acc[cb][nb] = MFMA_B16(xf[nb], wf, acc[cb][nb]);   // col=c, row=n
      } else {
#pragma unroll
        for (int nb = 0; nb < 4; nb++)
          acc[cb][nb] = MFMA_B16(wf, xf[nb], acc[cb][nb]);   // col=n, row=c
      }
    }
  }
  if (tau < 2) {
    short* out = tau ? kt : qt;
    float scale = tau ? 1.0f : (0.125f * 1.44269504f);  // fold 1/sqrt(64), log2e into Q
#pragma unroll
    for (int cb = 0; cb < 4; cb++) {
      int c = 64 * w + 16 * cb + lo;
      float bvv = bias[c];
      int h = c & 3, d = c >> 2;
      size_t base = (size_t)(b * 4 + h) * 64;
#pragma unroll
      for (int nb = 0; nb < 4; nb++) {
#pragma unroll
        for (int r = 0; r < 4; r++) {
          int n = n0 + 16 * nb + 4 * hi + r;
          size_t addr = (((base + (n >> 5)) * 4 + (d >> 4)) * 64 +
                         (n & 31) + 32 * ((d >> 3) & 1)) * 8 + (d & 7);
          out[addr] = f2bf((acc[cb][nb][r] + bvv) * scale);
        }
      }
    }
  } else {
#pragma unroll
    for (int cb = 0; cb < 4; cb++) {
#pragma unroll
      for (int r = 0; r < 4; r++) {
        int c = 64 * w + 16 * cb + 4 * hi + r;
        float bvv = bias[c];
        int h = c & 3, d = c >> 2;
        size_t base = (size_t)(b * 4 + h) * 128;
#pragma unroll
        for (int nb = 0; nb < 4; nb++) {
          int m = n0 + 16 * nb + lo;
          size_t addr = (((base + (m >> 4)) * 2 + (d >> 5)) * 64 +
                         (d & 31) + 32 * ((m >> 3) & 1)) * 8 + (m & 7);
          vt[addr] = f2bf(acc[cb][nb][r] + bvv);
        }
      }
    }
  }
}

// Flash attention, 32x32x16 MFMA, fully in-register P. 8 waves x 32 n = 256-row
// Q tiles. Swapped QK^T; P redistributed via v_cvt_pk_bf16_f32 + permlane32_swap.
// No-max softmax; per-lane row-sum + one shfl_xor(32).
// T4 pipeline: 3-deep LDS buffers, counted s_waitcnt vmcnt(2) + RAW s_barrier
// (never drain to 0 in the loop) -- tile t+2's loads stay in flight across the
// barrier; lgkmcnt(0) before barrier closes the reuse-after-3 write hazard.
// SPLIT==4: 1-D grid 512 with XCD-aware decode (T1, bijective).
template <int SPLIT>
__global__ __launch_bounds__(512, 4) void k_attn(const short* __restrict__ qt,
    const short* __restrict__ kt, const short* __restrict__ vt,
    short* __restrict__ opart, float* __restrict__ ml) {
  __shared__ __align__(16) short Ks[3][4096];   // [m32(2)][dk(4)][lane][8]
  __shared__ __align__(16) short Vs[3][4096];   // [m16(4)][dcol(2)][lane][8]
  int b, h, chunk, n0;
  if (SPLIT == 4) {
    int bid = blockIdx.x;
    int xcd = bid & 7, slot = bid >> 3;
    int g = xcd + 8 * (slot >> 3);    // group 0..63, g%8 == xcd
    n0 = (slot & 7) * 256;            // q-tile within group
    h = g & 3;
    int zz = g >> 2;                  // 0..15
    b = zz & 3;
    chunk = zz >> 2;
  } else {
    b = blockIdx.z & 3; chunk = 0; h = blockIdx.y; n0 = blockIdx.x * 256;
  }
  int tid = threadIdx.x;
  int lane = tid & 63, w = tid >> 6;
  int l31 = lane & 31, hi2 = lane >> 5;
  const int CH = NTOK / SPLIT;
  const int kv0 = chunk * CH;
  int bh = b * 4 + h;
  const short* Qf = qt + (size_t)bh * 131072;
  const short* Kf = kt + (size_t)bh * 131072;
  const short* Vf = vt + (size_t)bh * 131072;
  short8 qf[4];
#pragma unroll
  for (int dk = 0; dk < 4; dk++)
    qf[dk] = *(const short8*)(Qf + (((size_t)((n0 >> 5) + w) * 4 + dk) * 64 + lane) * 8);
  f32x16 acc[2] = {};
  float lacc = 0.0f;

  const int nt = CH >> 6;   // 8 (SPLIT=4) or 32 (SPLIT=1)
  // prologue: stage tiles 0 and 1, one-time full drain
  {
    int m0 = kv0;
    gload16(Kf + (size_t)(m0 >> 5) * 2048 + tid * 8, &Ks[0][tid * 8]);
    gload16(Vf + (size_t)(m0 >> 4) * 1024 + tid * 8, &Vs[0][tid * 8]);
    int m1 = kv0 + 64;
    gload16(Kf + (size_t)(m1 >> 5) * 2048 + tid * 8, &Ks[1][tid * 8]);
    gload16(Vf + (size_t)(m1 >> 4) * 1024 + tid * 8, &Vs[1][tid * 8]);
  }
  asm volatile("s_waitcnt vmcnt(0)" ::: "memory");
  __builtin_amdgcn_s_barrier();
  __builtin_amdgcn_sched_barrier(0);

#pragma unroll
  for (int t = 0; t < nt; t++) {
    int cur = t % 3;
    if (t + 2 < nt) {
      int m2 = kv0 + ((t + 2) << 6);
      int nxt = (t + 2) % 3;
      gload16(Kf + (size_t)(m2 >> 5) * 2048 + tid * 8, &Ks[nxt][tid * 8]);
      gload16(Vf + (size_t)(m2 >> 4) * 1024 + tid * 8, &Vs[nxt][tid * 8]);
    }
#pragma unroll
    for (int mb2 = 0; mb2 < 2; mb2++) {
      // ---- QK^T: S[m 32][n 32], chained over 4 k-slices of d ----
      f32x16 s = {};
      __builtin_amdgcn_s_setprio(1);
#pragma unroll
      for (int dk = 0; dk < 4; dk++) {
        short8 kf = *(const short8*)&Ks[cur][(mb2 * 4 + dk) * 512 + lane * 8];
        s = MFMA32(kf, qf[dk], s);
      }
      __builtin_amdgcn_s_setprio(0);
      // ---- softmax + in-register P->A redistribution + PV ----
#pragma unroll
      for (int ks = 0; ks < 2; ks++) {
        float e0 = exp2f(s[ks * 8 + 0]), e1 = exp2f(s[ks * 8 + 1]);
        float e2 = exp2f(s[ks * 8 + 2]), e3 = exp2f(s[ks * 8 + 3]);
        float e4 = exp2f(s[ks * 8 + 4]), e5 = exp2f(s[ks * 8 + 5]);
        float e6 = exp2f(s[ks * 8 + 6]), e7 = exp2f(s[ks * 8 + 7]);
        lacc += ((e0 + e1) + (e2 + e3)) + ((e4 + e5) + (e6 + e7));
        unsigned A, B, C2, D2;
        asm("v_cvt_pk_bf16_f32 %0, %1, %2" : "=v"(A) : "v"(e0), "v"(e1));
        asm("v_cvt_pk_bf16_f32 %0, %1, %2" : "=v"(C2) : "v"(e2), "v"(e3));
        asm("v_cvt_pk_bf16_f32 %0, %1, %2" : "=v"(B) : "v"(e4), "v"(e5));
        asm("v_cvt_pk_bf16_f32 %0, %1, %2" : "=v"(D2) : "v"(e6), "v"(e7));
        // swap: A' = (A_lo, B_lo) = pa w0;  B' = (A_hi, B_hi) = pa w2
        asm("v_permlane32_swap_b32 %0, %1" : "+v"(A), "+v"(B));
        asm("v_permlane32_swap_b32 %0, %1" : "+v"(C2), "+v"(D2));
        union { unsigned u[4]; short8 v8; } pu;
        pu.u[0] = A; pu.u[1] = C2; pu.u[2] = B; pu.u[3] = D2;
        __builtin_amdgcn_s_setprio(1);
#pragma unroll
        for (int dcol = 0; dcol < 2; dcol++) {
          short8 vf = *(const short8*)&Vs[cur][((mb2 * 2 + ks) * 2 + dcol) * 512 + lane * 8];
          acc[dcol] = MFMA32(pu.v8, vf, acc[dcol]);
        }
        __builtin_amdgcn_s_setprio(0);
      }
    }
    // counted wait: ensure tile t+1 resident; keep t+2's loads in flight.
    if (t + 1 < nt) {
      if (t + 2 < nt)
        asm volatile("s_waitcnt vmcnt(2) lgkmcnt(0)" ::: "memory");
      else
        asm volatile("s_waitcnt vmcnt(0) lgkmcnt(0)" ::: "memory");
      __builtin_amdgcn_s_barrier();
      __builtin_amdgcn_sched_barrier(0);
    }
  }

  // row-sum: combine the two lane-halves (same n at lane and lane^32)
  float l = lacc + __shfl_xor(lacc, 32);
  size_t rbase = (((size_t)chunk * NB4 + b) * 4 + h) * NTOK;
  if (lane < 32) ml[rbase + n0 + 32 * w + lane] = l;
#pragma unroll
  for (int r = 0; r < 16; r++) {
    int n = n0 + 32 * w + (r & 3) + 8 * (r >> 2) + 4 * hi2;
#pragma unroll
    for (int dcol = 0; dcol < 2; dcol++)
      opart[(rbase + n) * HD + dcol * 32 + l31] = f2bf(acc[dcol][r]);
  }
}

// Fused combine + output GEMM, c0-merged: block = 32 n-rows x ALL 256 c.
// Additive combine -> As (fragment-linear, XOR-swizzled); wave = 64c x 32n.
template <int NCH>
__global__ __launch_bounds__(256, 4) void k_out(const short* __restrict__ W,
    const short* __restrict__ opart, const float* __restrict__ ml,
    const float* __restrict__ bias, float* __restrict__ outp) {
  __shared__ __align__(16) short As[8192];  // [nb(2)][i32(8)][64][8], swizzled
  int b = blockIdx.y;
  int n0 = blockIdx.x * 32;
  int t = threadIdx.x;
  int lane = t & 63, w = t >> 6;
  int lo16 = lane & 15, hi = lane >> 4;
  {
    int d8 = t & 7, h = (t >> 3) & 3, nb8 = t >> 5;   // nb8 0..7
    int i32 = 2 * h + (d8 >> 2), fhi = d8 & 3;        // fragment coords of i'
#pragma unroll
    for (int it = 0; it < 4; it++) {
      int noff = nb8 * 4 + it;                        // 0..31
      int n = n0 + noff;
      int nb = noff >> 4, flo = noff & 15;
      size_t row0 = ((size_t)b * 4 + h) * NTOK + n;   // chunk 0
      float l = ml[row0];
      float o[8];
      short8 o0 = *(const short8*)(opart + row0 * HD + d8 * 8);
#pragma unroll
      for (int j = 0; j < 8; j++) o[j] = bf2f(o0[j]);
#pragma unroll
      for (int ch = 1; ch < NCH; ch++) {
        size_t rowc = row0 + (size_t)ch * 16 * NTOK;
        l += ml[rowc];
        short8 oc = *(const short8*)(opart + rowc * HD + d8 * 8);
#pragma unroll
        for (int j = 0; j < 8; j++) o[j] += bf2f(oc[j]);
      }
      float inv = 1.0f / l;
      short8 res;
#pragma unroll
      for (int j = 0; j < 8; j++) res[j] = f2bf(o[j] * inv);
      int frag = ((nb * 8 + i32) * 64 + fhi * 16 + flo) ^ d8;  // d8==fhi|((i32&1)<<2)
      *(short8*)(As + frag * 8) = res;
    }
  }
  __syncthreads();
  f32x4 acc[4][2] = {};   // [cb][nb]
  const short* arow = W + (size_t)(64 * w + lo16) * DM + hi * 8;
#pragma unroll
  for (int ks = 0; ks < 8; ks++) {
    int sr = hi | ((ks & 1) << 2);
    short8 bbr[2];
#pragma unroll
    for (int nb = 0; nb < 2; nb++) {
      int frag = ((nb * 8 + ks) * 64 + lane) ^ sr;
      bbr[nb] = *(const short8*)(As + frag * 8);
    }
#pragma unroll
    for (int cb = 0; cb < 4; cb++) {
      short8 a = *(const short8*)(arow + (size_t)cb * 16 * DM + ks * 32);
#pragma unroll
      for (int nb = 0; nb < 2; nb++)
        acc[cb][nb] = MFMA_B16(a, bbr[nb], acc[cb][nb]);
    }
  }
#pragma unroll
  for (int cb = 0; cb < 4; cb++) {
#pragma unroll
    for (int r = 0; r < 4; r++) {
      int c = 64 * w + 16 * cb + 4 * hi + r;
      float bvv = bias[c];
#pragma unroll
      for (int nb = 0; nb < 2; nb++) {
        int n = n0 + 16 * nb + lo16;
        outp[((size_t)b * DM + c) * NTOK + n] = acc[cb][nb][r] + bvv;
      }
    }
  }
}

extern "C" void kernel_launch(void* const* d_in, const int* in_sizes, int n_in,
                              void* d_out, int out_size, void* d_ws, size_t ws_size,
                              hipStream_t stream) {
  const float* q  = (const float*)d_in[0];
  const float* k  = (const float*)d_in[1];
  const float* v  = (const float*)d_in[2];
  const float* wq = (const float*)d_in[3];
  const float* bq = (const float*)d_in[4];
  const float* wk = (const float*)d_in[5];
  const float* bk = (const float*)d_in[6];
  const float* wv = (const float*)d_in[7];
  const float* bv = (const float*)d_in[8];
  const float* wm = (const float*)d_in[9];
  const float* bm = (const float*)d_in[10];

  char* ws = (char*)d_ws;
  const size_t MB = 1024 * 1024;
  short* Qt  = (short*)(ws);              // 4MB  Q fragments (32-wide)
  short* Kt  = (short*)(ws + 4 * MB);     // 4MB  K fragments
  short* Vt  = (short*)(ws + 8 * MB);     // 4MB  V fragments
  short* Wbf = (short*)(ws + 12 * MB);    // 4 x 128KB
  float* ML    = (float*)(ws + 13 * MB);  // 4 chunks x 128KB row sums l
  short* Opart = (short*)(ws + 14 * MB);  // 4 chunks x 4MB bf16 partial O

  k_wpre<<<dim3(32), 256, 0, stream>>>(wq, wk, wv, wm, Wbf);
  k_proj<<<dim3(32, 12), 256, 0, stream>>>(q, k, v, Wbf, bq, bk, bv, Qt, Kt, Vt);

  if (ws_size >= 32 * MB) {
    k_attn<4><<<dim3(512), 512, 0, stream>>>(Qt, Kt, Vt, Opart, ML);
    k_out<4><<<dim3(64, 4), 256, 0, stream>>>(Wbf + 3 * 65536, Opart, ML, bm, (float*)d_out);
  } else {
    k_attn<1><<<dim3(8, 4, 4), 512, 0, stream>>>(Qt, Kt, Vt, Opart, ML);
    k_out<1><<<dim3(64, 4), 256, 0, stream>>>(Wbf + 3 * 65536, Opart, ML, bm, (float*)d_out);
  }

  (void)in_sizes; (void)n_in; (void)out_size; (void)ws_size;
}